// Round 7
// baseline (314.536 us; speedup 1.0000x reference)
//
#include <hip/hip_runtime.h>
#include <limits.h>

#define THREADS 256
#define GRID_BLOCKS 896

typedef int vi4 __attribute__((ext_vector_type(4)));

__device__ __forceinline__ float clamp8f(float q) { return fminf(fmaxf(q, -128.0f), 127.0f); }
__device__ __forceinline__ float sc_from_bits(unsigned b) {
  return fmaxf(__uint_as_float(b) / 127.0f, 1e-8f);
}
__device__ __forceinline__ signed char q8(float v, float s) {
  return (signed char)(int)clamp8f(rintf(v / s));
}

// Scalar slots: [0] amax_x [1] amax_w1 [2] amax_w2 [3] amax_wid
// [4] maxabs_h1 [5] maxabs_id [6] maxabs_h2 [7] max_y2(rf bits) [9] s_y2 [10] s_idq [11] amax_sum
// Grid barriers (zeroed by hipMemsetAsync of IS[128..1024) each launch, graph-replay safe):
//   bases: k_pq 128; k_cv1 288,448; k_tail 608,768. Per base B: subs B+s*16 (s<8), root B+128,
//   flag B+144. All value slots use SIGNED atomicMax; 0xAA poison is negative -> no init pass.
// r5 lesson: 2016-block barrier needs (256,8) -> 64 VGPR -> load pipelining dies. r7: 896-block
// merged front at (256,4) -> 128 VGPR; x held in 56 registers across the barrier, read ONCE.

__device__ __forceinline__ void gbar(int* IS, int base, int bx, int subTgt) {
  // fence-free barrier (r3-proven): relaxed hierarchical arrive + relaxed system poll.
  // __syncthreads before the call drains every wave's vmem (hipcc emits s_waitcnt vmcnt(0)
  // before s_barrier), so all block stores/atomics are at the coherence point before arrive.
  asm volatile("s_waitcnt vmcnt(0)" ::: "memory");  // caller tid0's own RMWs
  int old = __hip_atomic_fetch_add(IS + base + (bx & 7) * 16, 1, __ATOMIC_RELAXED,
                                   __HIP_MEMORY_SCOPE_AGENT);
  if (old == subTgt - 1) {
    int r = __hip_atomic_fetch_add(IS + base + 128, 1, __ATOMIC_RELAXED, __HIP_MEMORY_SCOPE_AGENT);
    if (r == 7)
      __hip_atomic_fetch_add(IS + base + 144, 1, __ATOMIC_RELAXED, __HIP_MEMORY_SCOPE_AGENT);
  }
  while (__hip_atomic_load(IS + base + 144, __ATOMIC_RELAXED, __HIP_MEMORY_SCOPE_SYSTEM) == 0)
    __builtin_amdgcn_s_sleep(2);
}

__device__ __forceinline__ float sc_slot(const int* IS, int slot) {
  unsigned u = (unsigned)__hip_atomic_load((int*)(IS + slot), __ATOMIC_RELAXED,
                                           __HIP_MEMORY_SCOPE_AGENT);
  return fmaxf(__uint_as_float(u) / 127.0f, 1e-8f);
}

// Merged pre+quant: 896 blocks, (256,4) -> full 128-VGPR budget, all co-resident.
// Block b owns x slices s=2b,2b+1 (slice s -> n=s/56,h=s%56; 7168 floats each, 28/thread).
// Phase A: x loaded into xs[56] REGISTERS (statically indexed) -> amax; wave-parallel weight
// amax (wave wvg=bx*4+wv of 3584: w1 1152 | w2 2304 | wid 128 waves, 64 float4/wave = exact);
// bnfold on blocks 0-2. gbar. Phase B: weight quant rides on t<64 (item g=bx*64+t, 57344=896*64
// exact, tt&63==t preserves coalescing); x quantized FROM REGISTERS via the conflict-benign
// scalar LDS transpose (r6 float4 variant byte-merged 4 lanes/word -> reverted).
__global__ __launch_bounds__(THREADS, 4) void k_pq(
    int* IS, const float* g1, const float* be1, const float* m1, const float* v1, float* wq1,
    float* b1, const float* g2, const float* be2, const float* m2, const float* v2, float* wq2,
    float* b2, const float* gi, const float* bei, const float* mi, const float* vvi, float* wqi,
    float* bi, const float* __restrict__ x, int* __restrict__ X8, const float* __restrict__ w1f,
    vi4* __restrict__ W1m, const float* __restrict__ w2f, vi4* __restrict__ W2m,
    const float* __restrict__ widf, vi4* __restrict__ Widm) {
  __shared__ signed char tile[56 * 132];
  __shared__ float red[THREADS];
  __shared__ float wred[4];
  __shared__ float sS[4];
  const int bx = blockIdx.x;
  const int t = threadIdx.x;
  const int lane = t & 63, wv = t >> 6;

  const int s0 = bx * 2;
  const int n0 = s0 / 56, h0 = s0 % 56;
  const int n1 = (s0 + 1) / 56, h1 = (s0 + 1) % 56;
  const float* xp0 = x + ((n0 * 128) * 56 + h0) * 56;
  const float* xp1 = x + ((n1 * 128) * 56 + h1) * 56;

  // ---- phase A: load x once into registers, amax ----
  float xs[56];
#pragma unroll
  for (int k = 0; k < 28; ++k) {
    int i = t + k * 256;  // < 7168
    xs[k] = xp0[(i / 56) * 3136 + (i % 56)];
  }
#pragma unroll
  for (int k = 0; k < 28; ++k) {
    int i = t + k * 256;
    xs[28 + k] = xp1[(i / 56) * 3136 + (i % 56)];
  }
  float m = 0.0f;
#pragma unroll
  for (int k = 0; k < 56; ++k) m = fmaxf(m, fabsf(xs[k]));

  // wave-parallel weight amax (one float4/lane)
  {
    int wvg = bx * 4 + wv;  // 0..3583
    const float4* wp;
    int* slot;
    int g;
    if (wvg < 1152) { wp = (const float4*)w1f; slot = IS + 1; g = wvg * 64 + lane; }
    else if (wvg < 3456) { wp = (const float4*)w2f; slot = IS + 2; g = (wvg - 1152) * 64 + lane; }
    else { wp = (const float4*)widf; slot = IS + 3; g = (wvg - 3456) * 64 + lane; }
    float4 v = wp[g];
    float wm = fmaxf(fmaxf(fabsf(v.x), fabsf(v.y)), fmaxf(fabsf(v.z), fabsf(v.w)));
#pragma unroll
    for (int k = 32; k >= 1; k >>= 1) wm = fmaxf(wm, __shfl_xor(wm, k));
    if (lane == 0) atomicMax(slot, __float_as_int(wm));
  }

  // bnfold (blocks 0-2; block-uniform branch, internal syncs safe)
  if (bx < 3) {
    const float *gamma, *beta, *mean, *var;
    float *wq, *bb;
    if (bx == 0) { gamma = g1; beta = be1; mean = m1; var = v1; wq = wq1; bb = b1; }
    else if (bx == 1) { gamma = g2; beta = be2; mean = m2; var = v2; wq = wq2; bb = b2; }
    else { gamma = gi; beta = bei; mean = mi; var = vvi; wq = wqi; bb = bi; }
    float ws = gamma[t] * (1.0f / sqrtf(var[t] + 1e-5f));
    red[t] = fabsf(ws);
    __syncthreads();
    for (int s = THREADS / 2; s > 0; s >>= 1) {
      if (t < s) red[t] = fmaxf(red[t], red[t + s]);
      __syncthreads();
    }
    float sws = fmaxf(red[0] / 127.0f, 1e-8f);
    float q = clamp8f(rintf(ws / sws)) * sws;
    wq[t] = q;  // plain stores: consumed by k_cv1/k_tail across kernel boundary
    bb[t] = beta[t] - mean[t] * q;
  }

  // block x-amax reduce -> IS[0]; then barrier
#pragma unroll
  for (int k = 32; k >= 1; k >>= 1) m = fmaxf(m, __shfl_xor(m, k));
  if (lane == 0) wred[wv] = m;
  __syncthreads();  // wred visible; all waves' vmem (weight atomics, bnfold) drained
  if (t == 0) {
    m = fmaxf(fmaxf(wred[0], wred[1]), fmaxf(wred[2], wred[3]));
    atomicMax(IS + 0, __float_as_int(m));
    gbar(IS, 128, bx, 112);  // all amax RMWs global
    sS[0] = sc_slot(IS, 0);
    sS[1] = sc_slot(IS, 1);
    sS[2] = sc_slot(IS, 2);
    sS[3] = sc_slot(IS, 3);
  }
  __syncthreads();

  // ---- phase B: weight quant ride-along (t<64), one item per thread ----
  if (t < 64) {
    int g = bx * 64 + t;  // < 57344
    if (g < 18432) {
      int tt = g;
      float s = sS[1];
      int lane2 = tt & 63;
      int cotile = (tt >> 6) & 15;
      int ks = tt >> 10;  // 0..17
      int tap = ks >> 1, kc = ks & 1;
      int kh = tap / 3, kw = tap % 3;
      int co = cotile * 16 + (lane2 & 15);
      int ci0 = kc * 64 + (lane2 >> 4) * 16;
      const float* src = w1f + (co * 128 + ci0) * 9 + kh * 3 + kw;
      int r[4];
#pragma unroll
      for (int q = 0; q < 4; ++q) {
        unsigned b0 = (unsigned char)q8(src[(q * 4 + 0) * 9], s);
        unsigned b1v = (unsigned char)q8(src[(q * 4 + 1) * 9], s);
        unsigned b2v = (unsigned char)q8(src[(q * 4 + 2) * 9], s);
        unsigned b3 = (unsigned char)q8(src[(q * 4 + 3) * 9], s);
        r[q] = (int)(b0 | (b1v << 8) | (b2v << 16) | (b3 << 24));
      }
      vi4 v = {r[0], r[1], r[2], r[3]};
      W1m[tt] = v;
    } else if (g < 55296) {
      int tt = g - 18432;  // < 36864
      float s = sS[2];
      int lane2 = tt & 63;
      int cotile = (tt >> 6) & 15;
      int ks = tt >> 10;  // 0..35
      int tap = ks >> 2, kc = ks & 3;
      int kh = tap / 3, kw = tap % 3;
      int co = cotile * 16 + (lane2 & 15);
      int ci0 = kc * 64 + (lane2 >> 4) * 16;
      const float* src = w2f + (co * 256 + ci0) * 9 + kh * 3 + kw;
      int r[4];
#pragma unroll
      for (int q = 0; q < 4; ++q) {
        unsigned b0 = (unsigned char)q8(src[(q * 4 + 0) * 9], s);
        unsigned b1v = (unsigned char)q8(src[(q * 4 + 1) * 9], s);
        unsigned b2v = (unsigned char)q8(src[(q * 4 + 2) * 9], s);
        unsigned b3 = (unsigned char)q8(src[(q * 4 + 3) * 9], s);
        r[q] = (int)(b0 | (b1v << 8) | (b2v << 16) | (b3 << 24));
      }
      vi4 v = {r[0], r[1], r[2], r[3]};
      W2m[tt] = v;
    } else {
      int tt = g - 55296;  // < 2048
      float s = sS[3];
      int lane2 = tt & 63;
      int cotile = (tt >> 6) & 15;
      int ks = tt >> 10;  // 0..1
      int co = cotile * 16 + (lane2 & 15);
      int ci0 = ks * 64 + (lane2 >> 4) * 16;
      const float* src = widf + co * 128 + ci0;
      int r[4];
#pragma unroll
      for (int q = 0; q < 4; ++q) {
        unsigned b0 = (unsigned char)q8(src[q * 4 + 0], s);
        unsigned b1v = (unsigned char)q8(src[q * 4 + 1], s);
        unsigned b2v = (unsigned char)q8(src[q * 4 + 2], s);
        unsigned b3 = (unsigned char)q8(src[q * 4 + 3], s);
        r[q] = (int)(b0 | (b1v << 8) | (b2v << 16) | (b3 << 24));
      }
      vi4 v = {r[0], r[1], r[2], r[3]};
      Widm[tt] = v;
    }
  }

  // ---- phase B: x quant from registers, two slices through the LDS transpose ----
  const float sx = sS[0];
#pragma unroll
  for (int k = 0; k < 28; ++k) {
    int i = t + k * 256;
    tile[(i % 56) * 132 + (i / 56)] = q8(xs[k], sx);
  }
  __syncthreads();
  {
    int* op = X8 + (n0 * 56 + h0) * 56 * 32;
#pragma unroll
    for (int k = 0; k < 7; ++k) {
      int i = t + k * 256;  // < 1792
      int w = i >> 5, c4 = (i & 31) * 4;
      const signed char* tp = tile + w * 132 + c4;
      op[i] = (int)(unsigned char)tp[0] | ((int)(unsigned char)tp[1] << 8) |
              ((int)(unsigned char)tp[2] << 16) | ((int)(unsigned char)tp[3] << 24);
    }
  }
  __syncthreads();  // pack reads done before tile overwrite
#pragma unroll
  for (int k = 0; k < 28; ++k) {
    int i = t + k * 256;
    tile[(i % 56) * 132 + (i / 56)] = q8(xs[28 + k], sx);
  }
  __syncthreads();
  {
    int* op = X8 + (n1 * 56 + h1) * 56 * 32;
#pragma unroll
    for (int k = 0; k < 7; ++k) {
      int i = t + k * 256;
      int w = i >> 5, c4 = (i & 31) * 4;
      const signed char* tp = tile + w * 132 + c4;
      op[i] = (int)(unsigned char)tp[0] | ((int)(unsigned char)tp[1] << 8) |
              ((int)(unsigned char)tp[2] << 16) | ((int)(unsigned char)tp[3] << 24);
    }
  }
}

#define MFMA_I8(a, b, c) __builtin_amdgcn_mfma_i32_16x16x64_i8(a, b, c, 0, 0, 0)

// quant(h1) -> bn1 -> relu -> quant (scalar form, used in k_cv1 qh1 phase)
__device__ __forceinline__ signed char qact(int v, float sxw, float s_h1, float s_y2, float wq,
                                            float bb) {
  float hf = (float)v * sxw;
  float q = clamp8f(rintf(hf / s_h1));
  float hv = q * s_h1;
  float y = fmaxf(hv * wq + bb, 0.0f);
  float a = fminf(fmaxf(rintf(y / s_y2), -128.0f), 127.0f);
  return (signed char)(int)a;
}

// Fused conv1 stage (r5 version): conv1 3x3 s2 p1 + identity 1x1 s2 + grid-wide scale
// derivation + qh1 => A2 int8, TWO fence-free barriers. Per-channel extrema stay in 8 VGPRs
// across B1; rf evaluated locally (monotone per channel => exact). H1 parked in LDS, never HBM.
// LDS staging XOR-swizzled stride-32 (37.1KB). (256,4): 1024 slots >= 896 co-resident.
__global__ __launch_bounds__(THREADS, 4) void k_cv1(const int* X8, const vi4* __restrict__ W1m,
                                                    const vi4* __restrict__ Widm,
                                                    int* __restrict__ IDI, int* A2i, int* IS,
                                                    const float* __restrict__ wq1,
                                                    const float* __restrict__ b1, float* SC) {
  __shared__ __align__(16) int lds[9280];  // stage 5*58*32; later park h1 [56][130]
  __shared__ int redA[4], redB[4];
  __shared__ float redF[4];
  __shared__ float sSxw, sSh1, sSy2;
  const int tid = threadIdx.x;
  const int bx = blockIdx.x;
  const int n = bx / 28, rr = bx % 28;
  const int hp = rr >> 1, nh = rr & 1;
  const int ho0 = hp * 2;
  vi4 zero = {0, 0, 0, 0};

  // ---- stage 5 input rows, swizzled stride-32 ----
  for (int r = 0; r < 5; ++r) {
    int h = 2 * ho0 - 1 + r;
    int* dst = lds + r * 58 * 32;
    if (h >= 0 && h < 56) {
      const vi4* src = (const vi4*)(X8 + (n * 56 + h) * 56 * 32);
      for (int i4 = tid; i4 < 448; i4 += THREADS) {
        int col = i4 >> 3, e0 = (i4 & 7) * 4;
        int cell = r * 58 + col + 1;
        *(vi4*)(lds + cell * 32 + (e0 ^ ((cell & 7) << 2))) = src[i4];
      }
      if (tid < 32) dst[tid] = 0;
      else if (tid >= 128 && tid < 160) dst[57 * 32 + (tid - 128)] = 0;
    } else {
      for (int i4 = tid; i4 < 464; i4 += THREADS) ((vi4*)dst)[i4] = zero;
    }
  }
  __syncthreads();

  const int lane = tid & 63, wv = tid >> 6;
  const int mw = wv & 1, nw = wv >> 1;
  const int lm = lane & 15, quad = lane >> 4;
  const int woc0 = lm, woc1 = (16 + lm) > 27 ? 27 : (16 + lm);
  const int choff = quad * 4;
  const int ho = ho0 + mw;
  const int obase = ((n * 28 + ho) * 28) * 256;
  const int ctbase = nh * 8 + nw * 4;

#define LDA(row, colp, sub)                                                              \
  (*(const vi4*)(lds + ((row) * 58 + (colp)) * 32 +                                      \
                 ((sub) ^ ((((row) * 58 + (colp)) & 7) << 2))))

  vi4 acc[2][4];
  vi4 bA[4], bB[4];
  vi4 a0A, a1A, a0B, a1B;

  // ---- identity branch first (2 K-steps) ----
#pragma unroll
  for (int mt = 0; mt < 2; ++mt)
#pragma unroll
    for (int ct = 0; ct < 4; ++ct) acc[mt][ct] = zero;
  const vi4* wibase = Widm + ctbase * 64 + lane;
  {
    const int row = 2 * mw + 1;
#pragma unroll
    for (int kc = 0; kc < 2; ++kc) {
      vi4 a0 = LDA(row, 2 * woc0 + 1, kc * 16 + choff);
      vi4 a1 = LDA(row, 2 * woc1 + 1, kc * 16 + choff);
#pragma unroll
      for (int ct = 0; ct < 4; ++ct) {
        vi4 b = wibase[kc * 1024 + ct * 64];
        acc[0][ct] = MFMA_I8(a0, b, acc[0][ct]);
        acc[1][ct] = MFMA_I8(a1, b, acc[1][ct]);
      }
    }
  }
  int am = 0;
#pragma unroll
  for (int ct = 0; ct < 4; ++ct) {
    const int co = (ctbase + ct) * 16 + lm;
#pragma unroll
    for (int mt = 0; mt < 2; ++mt)
#pragma unroll
      for (int r = 0; r < 4; ++r) {
        int wo = mt * 16 + quad * 4 + r;
        if (wo < 28) {
          int v = acc[mt][ct][r];
          IDI[obase + wo * 256 + co] = v;  // plain store: consumed by k_tail after boundary
          am = max(am, v < 0 ? -v : v);
        }
      }
  }
#pragma unroll
  for (int k = 32; k >= 1; k >>= 1) am = max(am, __shfl_xor(am, k));
  if (lane == 0) redA[wv] = am;

  // ---- main 3x3 conv, 18 K-steps, ping-pong ----
#pragma unroll
  for (int mt = 0; mt < 2; ++mt)
#pragma unroll
    for (int ct = 0; ct < 4; ++ct) acc[mt][ct] = zero;
  const vi4* wbase = W1m + ctbase * 64 + lane;
#pragma unroll
  for (int ct = 0; ct < 4; ++ct) bA[ct] = wbase[ct * 64];
  {
    a0A = LDA(2 * mw, 2 * woc0, choff);
    a1A = LDA(2 * mw, 2 * woc1, choff);
  }
#pragma unroll 1
  for (int ks = 0; ks < 18; ks += 2) {
    {
      const int ksn = ks + 1;
      const int khn = (ksn >= 6) + (ksn >= 12);
      const int t2 = ksn - khn * 6;
      const int kwn = t2 >> 1, kcn = t2 & 1;
#pragma unroll
      for (int ct = 0; ct < 4; ++ct) bB[ct] = wbase[ksn * 1024 + ct * 64];
      const int row = 2 * mw + khn;
      a0B = LDA(row, 2 * woc0 + kwn, kcn * 16 + choff);
      a1B = LDA(row, 2 * woc1 + kwn, kcn * 16 + choff);
    }
#pragma unroll
    for (int ct = 0; ct < 4; ++ct) {
      acc[0][ct] = MFMA_I8(a0A, bA[ct], acc[0][ct]);
      acc[1][ct] = MFMA_I8(a1A, bA[ct], acc[1][ct]);
    }
    if (ks + 2 < 18) {
      const int ksn = ks + 2;
      const int khn = (ksn >= 6) + (ksn >= 12);
      const int t2 = ksn - khn * 6;
      const int kwn = t2 >> 1, kcn = t2 & 1;
#pragma unroll
      for (int ct = 0; ct < 4; ++ct) bA[ct] = wbase[ksn * 1024 + ct * 64];
      const int row = 2 * mw + khn;
      a0A = LDA(row, 2 * woc0 + kwn, kcn * 16 + choff);
      a1A = LDA(row, 2 * woc1 + kwn, kcn * 16 + choff);
    }
#pragma unroll
    for (int ct = 0; ct < 4; ++ct) {
      acc[0][ct] = MFMA_I8(a0B, bB[ct], acc[0][ct]);
      acc[1][ct] = MFMA_I8(a1B, bB[ct], acc[1][ct]);
    }
  }

  // ---- per-channel extrema in REGISTERS + block absmax(h1) ----
  int vmx[4], vmn[4];
  int am1 = 0;
#pragma unroll
  for (int ct = 0; ct < 4; ++ct) {
    int vmax = INT_MIN, vmin = INT_MAX;
#pragma unroll
    for (int mt = 0; mt < 2; ++mt)
#pragma unroll
      for (int r = 0; r < 4; ++r) {
        int wo = mt * 16 + quad * 4 + r;
        if (wo < 28) {
          int v = acc[mt][ct][r];
          vmax = max(vmax, v);
          vmin = min(vmin, v);
        }
      }
    vmax = max(vmax, __shfl_xor(vmax, 16));
    vmax = max(vmax, __shfl_xor(vmax, 32));
    vmin = min(vmin, __shfl_xor(vmin, 16));
    vmin = min(vmin, __shfl_xor(vmin, 32));
    vmx[ct] = vmax;
    vmn[ct] = vmin;
    am1 = max(am1, max(vmax < 0 ? -vmax : vmax, vmin < 0 ? -vmin : vmin));
  }
#pragma unroll
  for (int k = 8; k >= 1; k >>= 1) am1 = max(am1, __shfl_xor(am1, k));
  if (lane == 0) redB[wv] = am1;

  __syncthreads();  // staging reads done -> park may overwrite; redA/redB ready
  // ---- park h1 into LDS [sp=mw*28+wo][130] ----
#pragma unroll
  for (int ct = 0; ct < 4; ++ct) {
    const int cl = (nw * 4 + ct) * 16 + lm;
#pragma unroll
    for (int mt = 0; mt < 2; ++mt)
#pragma unroll
      for (int r = 0; r < 4; ++r) {
        int wo = mt * 16 + quad * 4 + r;
        if (wo < 28) lds[(mw * 28 + wo) * 130 + cl] = acc[mt][ct][r];
      }
  }
  if (tid == 0) {
    atomicMax(IS + 5, max(max(redA[0], redA[1]), max(redA[2], redA[3])));
    atomicMax(IS + 4, max(max(redB[0], redB[1]), max(redB[2], redB[3])));
    gbar(IS, 288, bx, 112);  // B1: mh1 + id amax global
    float sx = sc_slot(IS, 0);
    float sw1 = sc_slot(IS, 1);
    int mh1 = __hip_atomic_load(IS + 4, __ATOMIC_RELAXED, __HIP_MEMORY_SCOPE_AGENT);
    sSxw = sx * sw1;
    sSh1 = fmaxf(sSxw * (float)mh1 / 127.0f, 1e-8f);
  }
  __syncthreads();

  // ---- local rf eval at own per-channel extrema (monotone => exact) ----
  {
    const float sxw = sSxw, s_h1 = sSh1;
    float ym = 0.0f;
#pragma unroll
    for (int ct = 0; ct < 4; ++ct) {
      const int co = (ctbase + ct) * 16 + lm;
      float wq = wq1[co], bbc = b1[co];
      float q1 = clamp8f(rintf((float)vmx[ct] * sxw / s_h1));
      float q0 = clamp8f(rintf((float)vmn[ct] * sxw / s_h1));
      float y1 = fmaxf(q1 * s_h1 * wq + bbc, 0.0f);
      float y0 = fmaxf(q0 * s_h1 * wq + bbc, 0.0f);
      ym = fmaxf(ym, fmaxf(y1, y0));
    }
#pragma unroll
    for (int k = 8; k >= 1; k >>= 1) ym = fmaxf(ym, __shfl_xor(ym, k));
    if (lane == 0) redF[wv] = ym;
  }
  __syncthreads();
  if (tid == 0) {
    atomicMax(IS + 7, __float_as_int(fmaxf(fmaxf(redF[0], redF[1]), fmaxf(redF[2], redF[3]))));
    gbar(IS, 448, bx, 112);  // B2: rf global (short gap after B1 -> tiny skew)
    int mrf = __hip_atomic_load(IS + 7, __ATOMIC_RELAXED, __HIP_MEMORY_SCOPE_AGENT);
    float s_y2 = fmaxf(__int_as_float(mrf) / 127.0f, 1e-8f);
    sSy2 = s_y2;
    if (bx == 0) {
      int mid = __hip_atomic_load(IS + 5, __ATOMIC_RELAXED, __HIP_MEMORY_SCOPE_AGENT);
      float sx = sc_slot(IS, 0);
      float swid = sc_slot(IS, 3);
      SC[9] = s_y2;  // plain stores: kernel-end flush -> visible to k_tail
      SC[10] = fmaxf(sx * swid * (float)mid / 127.0f, 1e-8f);
    }
  }
  __syncthreads();

  // ---- qh1 from parked LDS -> A2 int8 (NHWC, own channel-half), coalesced int writes ----
  {
    const float sxw = sSxw, s_h1 = sSh1, s_y2 = sSy2;
#pragma unroll
    for (int k = 0; k < 7; ++k) {
      int i = tid + k * 256;  // < 1792
      int sp = i >> 5, c4i = i & 31;
      int mwp = sp >= 28 ? 1 : 0;
      int wo = sp - mwp * 28;
      int c0 = nh * 128 + c4i * 4;
      const int* pk = lds + sp * 130 + c4i * 4;
      unsigned r0 = (unsigned char)qact(pk[0], sxw, s_h1, s_y2, wq1[c0], b1[c0]);
      unsigned r1 = (unsigned char)qact(pk[1], sxw, s_h1, s_y2, wq1[c0 + 1], b1[c0 + 1]);
      unsigned r2 = (unsigned char)qact(pk[2], sxw, s_h1, s_y2, wq1[c0 + 2], b1[c0 + 2]);
      unsigned r3 = (unsigned char)qact(pk[3], sxw, s_h1, s_y2, wq1[c0 + 3], b1[c0 + 3]);
      A2i[((n * 28 + ho0 + mwp) * 28 + wo) * 64 + nh * 32 + c4i] =
          (int)(r0 | (r1 << 8) | (r2 << 16) | (r3 << 24));
    }
  }
#undef LDA
}

// ---- residual sum math ----
struct SumParams {
  float sxw2, s_h2, sxwid, s_idq;
};
__device__ __forceinline__ float sum_val(int v2, int vi, const SumParams& P, float wq2c, float b2c,
                                         float wqidc, float bidc) {
  float q2 = clamp8f(rintf((float)v2 * P.sxw2 / P.s_h2));
  float z = (q2 * P.s_h2) * wq2c + b2c;
  float qi = clamp8f(rintf((float)vi * P.sxwid / P.s_idq));
  float zi = (qi * P.s_idq) * wqidc + bidc;
  return z + zi;
}
__device__ __forceinline__ SumParams make_params2(const float* SC, const unsigned* ISu, int mh2) {
  SumParams P;
  float sx = sc_from_bits(ISu[0]);
  float sw2 = sc_from_bits(ISu[2]);
  float swid = sc_from_bits(ISu[3]);
  float s_y2 = SC[9];
  P.s_idq = SC[10];
  P.sxw2 = s_y2 * sw2;
  P.s_h2 = fmaxf(P.sxw2 * (float)mh2 / 127.0f, 1e-8f);
  P.sxwid = sx * swid;
  return P;
}

// Fused tail (r3-proven, ~67us): conv2 3x3 s1 p1 (Cin=256) + residual absmax + requant + NCHW out.
// Fence-free grid barriers at bases 608/768. H2 never hits HBM.
__global__ __launch_bounds__(THREADS, 4) void k_tail(const int* __restrict__ A2,
                                                     const vi4* __restrict__ W2m,
                                                     const int* __restrict__ IDI,
                                                     const float* SC, int* IS,
                                                     const float* __restrict__ wq2,
                                                     const float* __restrict__ b2,
                                                     const float* __restrict__ wqid,
                                                     const float* __restrict__ bidp,
                                                     float* __restrict__ out) {
  __shared__ __align__(16) int lds[4 * 30 * 68];  // 32640B; reused for sums [128][57] f32
  __shared__ int redA[4];
  __shared__ float redF[4];
  __shared__ int sMh2;
  __shared__ float sOutS;
  const int tid = threadIdx.x;
  const int bx = blockIdx.x;
  const int n = bx / 28, rr = bx % 28;
  const int hp = rr >> 1, nh = rr & 1;
  const int ho0 = hp * 2;
  vi4 zero = {0, 0, 0, 0};

  for (int r = 0; r < 4; ++r) {
    int h = ho0 - 1 + r;
    int* dst = lds + r * 30 * 68;
    if (h >= 0 && h < 28) {
      const vi4* src = (const vi4*)(A2 + (n * 28 + h) * 28 * 64);
      for (int i4 = tid; i4 < 448; i4 += THREADS) {
        int col = i4 >> 4, c = (i4 & 15) * 4;
        *(vi4*)(dst + (col + 1) * 68 + c) = src[i4];
      }
      if (tid < 64) dst[tid] = 0;
      else if (tid >= 128 && tid < 192) dst[29 * 68 + (tid - 128)] = 0;
    } else {
      for (int i4 = tid; i4 < 510; i4 += THREADS) ((vi4*)dst)[i4] = zero;
    }
  }
  __syncthreads();

  const int lane = tid & 63, wv = tid >> 6;
  const int mw = wv & 1, nw = wv >> 1;
  const int lm = lane & 15, quad = lane >> 4;
  const int woc0 = lm, woc1 = (16 + lm) > 27 ? 27 : (16 + lm);
  const int choff = quad * 4;
  const int ctbase = nh * 8 + nw * 4;

  vi4 acc[2][4];
  vi4 bA[4], bB[4];
  vi4 a0A, a1A, a0B, a1B;
#pragma unroll
  for (int mt = 0; mt < 2; ++mt)
#pragma unroll
    for (int ct = 0; ct < 4; ++ct) acc[mt][ct] = zero;

  const vi4* wbase = W2m + ctbase * 64 + lane;
#pragma unroll
  for (int ct = 0; ct < 4; ++ct) bA[ct] = wbase[ct * 64];
  {
    const int ro = mw * 30;  // ks=0
    a0A = *(const vi4*)(lds + (ro + woc0) * 68 + choff);
    a1A = *(const vi4*)(lds + (ro + woc1) * 68 + choff);
  }
#pragma unroll 1
  for (int ks = 0; ks < 36; ks += 2) {
    {
      const int ksn = ks + 1;
      const int khn = (ksn >= 12) + (ksn >= 24);
      const int t2 = ksn - khn * 12;
      const int kwn = t2 >> 2, kcn = t2 & 3;
#pragma unroll
      for (int ct = 0; ct < 4; ++ct) bB[ct] = wbase[ksn * 1024 + ct * 64];
      const int ro = (mw + khn) * 30;
      a0B = *(const vi4*)(lds + (ro + woc0 + kwn) * 68 + kcn * 16 + choff);
      a1B = *(const vi4*)(lds + (ro + woc1 + kwn) * 68 + kcn * 16 + choff);
    }
#pragma unroll
    for (int ct = 0; ct < 4; ++ct) {
      acc[0][ct] = MFMA_I8(a0A, bA[ct], acc[0][ct]);
      acc[1][ct] = MFMA_I8(a1A, bA[ct], acc[1][ct]);
    }
    if (ks + 2 < 36) {
      const int ksn = ks + 2;
      const int khn = (ksn >= 12) + (ksn >= 24);
      const int t2 = ksn - khn * 12;
      const int kwn = t2 >> 2, kcn = t2 & 3;
#pragma unroll
      for (int ct = 0; ct < 4; ++ct) bA[ct] = wbase[ksn * 1024 + ct * 64];
      const int ro = (mw + khn) * 30;
      a0A = *(const vi4*)(lds + (ro + woc0 + kwn) * 68 + kcn * 16 + choff);
      a1A = *(const vi4*)(lds + (ro + woc1 + kwn) * 68 + kcn * 16 + choff);
    }
#pragma unroll
    for (int ct = 0; ct < 4; ++ct) {
      acc[0][ct] = MFMA_I8(a0B, bB[ct], acc[0][ct]);
      acc[1][ct] = MFMA_I8(a1B, bB[ct], acc[1][ct]);
    }
  }

  // ---- block max|h2| straight from acc (H2 never stored) ----
  int am = 0;
#pragma unroll
  for (int ct = 0; ct < 4; ++ct)
#pragma unroll
    for (int mt = 0; mt < 2; ++mt)
#pragma unroll
      for (int r = 0; r < 4; ++r) {
        int wo = mt * 16 + quad * 4 + r;
        if (wo < 28) {
          int v = acc[mt][ct][r];
          am = max(am, v < 0 ? -v : v);
        }
      }
#pragma unroll
  for (int k = 32; k >= 1; k >>= 1) am = max(am, __shfl_xor(am, k));
  if (lane == 0) redA[wv] = am;
  __syncthreads();
  if (tid == 0) {
    int a = max(max(redA[0], redA[1]), max(redA[2], redA[3]));
    atomicMax(IS + 6, a);  // device RMW (coherence point)
  }

  // ---- stage this block's IDI half into LDS, transposed [cl][sp] (pad 57) ----
  int* sumsi = lds;
  float* sums = (float*)lds;
  const int ib = ((n * 28 + ho0) * 28) * 256 + nh * 128;
#pragma unroll
  for (int k = 0; k < 28; ++k) {
    int idx = tid + k * 256;            // 0..7167
    int cl = idx & 127, sp = idx >> 7;  // sp = hl*28+wo
    sumsi[cl * 57 + sp] = IDI[ib + sp * 256 + cl];
  }
  __syncthreads();
  if (tid == 0) {
    gbar(IS, 608, bx, 112);  // B: max|h2| global
    sMh2 = __hip_atomic_load(IS + 6, __ATOMIC_RELAXED, __HIP_MEMORY_SCOPE_SYSTEM);
  }
  __syncthreads();
  const SumParams P = make_params2(SC, (const unsigned*)IS, sMh2);

  // ---- RMW owned slots: sum = z + zi; track |sum| ----
  float fm = 0.0f;
#pragma unroll
  for (int ct = 0; ct < 4; ++ct) {
    const int co = (ctbase + ct) * 16 + lm;
    const int cl = co - nh * 128;
    float w2c = wq2[co], b2c = b2[co], wic = wqid[co], bic = bidp[co];
#pragma unroll
    for (int mt = 0; mt < 2; ++mt)
#pragma unroll
      for (int r = 0; r < 4; ++r) {
        int wo = mt * 16 + quad * 4 + r;
        if (wo < 28) {
          int slot = cl * 57 + mw * 28 + wo;
          float sv = sum_val(acc[mt][ct][r], sumsi[slot], P, w2c, b2c, wic, bic);
          sums[slot] = sv;
          fm = fmaxf(fm, fabsf(sv));
        }
      }
  }
#pragma unroll
  for (int k = 32; k >= 1; k >>= 1) fm = fmaxf(fm, __shfl_xor(fm, k));
  if (lane == 0) redF[wv] = fm;
  __syncthreads();
  if (tid == 0) {
    float a = fmaxf(fmaxf(redF[0], redF[1]), fmaxf(redF[2], redF[3]));
    atomicMax(IS + 11, __float_as_int(a));
    gbar(IS, 768, bx, 112);  // B: max|sum| global
    int mb = __hip_atomic_load(IS + 11, __ATOMIC_RELAXED, __HIP_MEMORY_SCOPE_SYSTEM);
    sOutS = fmaxf(__int_as_float(mb) / 127.0f, 1e-8f);
  }
  __syncthreads();
  const float out_s = sOutS;

  // ---- requant + relu, NCHW write ----
  float* ob = out + n * 200704 + (nh * 128) * 784 + ho0 * 28;
#pragma unroll
  for (int k = 0; k < 28; ++k) {
    int idx = tid + k * 256;
    int cl = idx / 56, rem = idx % 56;
    float sv = sums[cl * 57 + rem];
    float q = clamp8f(rintf(sv / out_s));
    ob[cl * 784 + rem] = q > 0.0f ? q * out_s : 0.0f;
  }
  if (bx == 0 && tid == 0) out[6422528] = out_s;
}

extern "C" void kernel_launch(void* const* d_in, const int* in_sizes, int n_in, void* d_out,
                              int out_size, void* d_ws, size_t ws_size, hipStream_t stream) {
  (void)in_sizes; (void)n_in; (void)out_size; (void)ws_size;
  const float* x = (const float*)d_in[0];
  const float* w1 = (const float*)d_in[1];
  const float* w2 = (const float*)d_in[2];
  const float* wid = (const float*)d_in[3];
  const float* bn1g = (const float*)d_in[4];
  const float* bn1b = (const float*)d_in[5];
  const float* bn1m = (const float*)d_in[6];
  const float* bn1v = (const float*)d_in[7];
  const float* bn2g = (const float*)d_in[8];
  const float* bn2b = (const float*)d_in[9];
  const float* bn2m = (const float*)d_in[10];
  const float* bn2v = (const float*)d_in[11];
  const float* idg = (const float*)d_in[12];
  const float* idb = (const float*)d_in[13];
  const float* idm = (const float*)d_in[14];
  const float* idv = (const float*)d_in[15];

  char* ws = (char*)d_ws;
  float* SC = (float*)ws;
  int* IS = (int*)ws;
  // barrier counters occupy IS[128..1024); per-channel tables after:
  float* wq1 = (float*)(ws + 4096);
  float* b1 = (float*)(ws + 5120);
  float* wq2 = (float*)(ws + 6144);
  float* b2 = (float*)(ws + 7168);
  float* wqid = (float*)(ws + 8192);
  float* bid = (float*)(ws + 9216);
  char* X8 = ws + 16384;  // NHWC int8; A2 overlays (all X8 reads complete before qh1 writes)
  char* A2 = X8;
  char* W1m = X8 + 12845056;
  char* W2m = W1m + 294912;
  char* Widm = W2m + 589824;
  int* IDI = (int*)(Widm + 32768);
  float* out = (float*)d_out;

  // re-arm all grid-barrier counters (graph-capturable stream memset)
  hipMemsetAsync(ws + 512, 0, 3584, stream);  // IS[128..1024)

  k_pq<<<GRID_BLOCKS, THREADS, 0, stream>>>(IS, bn1g, bn1b, bn1m, bn1v, wq1, b1, bn2g, bn2b,
                                            bn2m, bn2v, wq2, b2, idg, idb, idm, idv, wqid, bid,
                                            x, (int*)X8, w1, (vi4*)W1m, w2, (vi4*)W2m, wid,
                                            (vi4*)Widm);
  k_cv1<<<GRID_BLOCKS, THREADS, 0, stream>>>((const int*)X8, (const vi4*)W1m, (const vi4*)Widm,
                                             IDI, (int*)A2, IS, wq1, b1, SC);
  k_tail<<<GRID_BLOCKS, THREADS, 0, stream>>>((const int*)A2, (const vi4*)W2m, (const int*)IDI, SC,
                                              IS, wq2, b2, wqid, bid, out);
}

// Round 8
// 262.531 us; speedup vs baseline: 1.1981x; 1.1981x over previous
//
#include <hip/hip_runtime.h>
#include <limits.h>

#define THREADS 256
#define GRID_BLOCKS 896

typedef int vi4 __attribute__((ext_vector_type(4)));

__device__ __forceinline__ float clamp8f(float q) { return fminf(fmaxf(q, -128.0f), 127.0f); }
__device__ __forceinline__ float sc_from_bits(unsigned b) {
  return fmaxf(__uint_as_float(b) / 127.0f, 1e-8f);
}
__device__ __forceinline__ signed char q8(float v, float s) {
  return (signed char)(int)clamp8f(rintf(v / s));
}

// Scalar slots: [0] amax_x [1] amax_w1 [2] amax_w2 [3] amax_wid
// [4] maxabs_h1 [5] maxabs_id [6] maxabs_h2 [7] max_y2(rf bits) [9] s_y2 [10] s_idq [11] amax_sum
// Grid barriers (zeroed by hipMemsetAsync of IS[128..1024) each launch, graph-replay safe):
//   bases: k_cv1 288,448; k_tail 608,768. Per base B: subs B+s*16 (s<8), root B+128, flag B+144.
// All value slots use SIGNED atomicMax; 0xAA poison is negative -> no init pass.
// r5/r7 lessons: grid-barrier fronts force VGPR caps that kill load pipelining (r5: (256,8)->64
// VGPR; r7: xs[56]@(256,4) spill). Front stays as two UNCAPPED kernels (r4-proven).
// r6 lesson candidate (this round disambiguates): float4 qx transpose byte-merges 4 lanes into
// one LDS word -> serialization; scalar transpose is conflict-benign.

__device__ __forceinline__ void gbar(int* IS, int base, int bx, int subTgt) {
  // fence-free barrier (r3-proven): relaxed hierarchical arrive + relaxed system poll.
  asm volatile("s_waitcnt vmcnt(0)" ::: "memory");  // caller tid0's own RMWs
  int old = __hip_atomic_fetch_add(IS + base + (bx & 7) * 16, 1, __ATOMIC_RELAXED,
                                   __HIP_MEMORY_SCOPE_AGENT);
  if (old == subTgt - 1) {
    int r = __hip_atomic_fetch_add(IS + base + 128, 1, __ATOMIC_RELAXED, __HIP_MEMORY_SCOPE_AGENT);
    if (r == 7)
      __hip_atomic_fetch_add(IS + base + 144, 1, __ATOMIC_RELAXED, __HIP_MEMORY_SCOPE_AGENT);
  }
  while (__hip_atomic_load(IS + base + 144, __ATOMIC_RELAXED, __HIP_MEMORY_SCOPE_SYSTEM) == 0)
    __builtin_amdgcn_s_sleep(2);
}

__device__ __forceinline__ void amax_body(const float4* __restrict__ p, int n4, int bid,
                                          int nblocks, int* __restrict__ slot) {
  const int tid = threadIdx.x;
  const int stride = nblocks * THREADS;
  float m = 0.0f;
  int i = bid * THREADS + tid;
  for (; i + 3 * stride < n4; i += 4 * stride) {
    float4 v0 = p[i];
    float4 v1 = p[i + stride];
    float4 v2 = p[i + 2 * stride];
    float4 v3 = p[i + 3 * stride];
    float m0 = fmaxf(fmaxf(fabsf(v0.x), fabsf(v0.y)), fmaxf(fabsf(v0.z), fabsf(v0.w)));
    float m1 = fmaxf(fmaxf(fabsf(v1.x), fabsf(v1.y)), fmaxf(fabsf(v1.z), fabsf(v1.w)));
    float m2 = fmaxf(fmaxf(fabsf(v2.x), fabsf(v2.y)), fmaxf(fabsf(v2.z), fabsf(v2.w)));
    float m3 = fmaxf(fmaxf(fabsf(v3.x), fabsf(v3.y)), fmaxf(fabsf(v3.z), fabsf(v3.w)));
    m = fmaxf(m, fmaxf(fmaxf(m0, m1), fmaxf(m2, m3)));
  }
  for (; i < n4; i += stride) {
    float4 v = p[i];
    m = fmaxf(m, fmaxf(fmaxf(fabsf(v.x), fabsf(v.y)), fmaxf(fabsf(v.z), fabsf(v.w))));
  }
#pragma unroll
  for (int k = 32; k >= 1; k >>= 1) m = fmaxf(m, __shfl_xor(m, k));
  __shared__ float wred[4];
  if ((tid & 63) == 0) wred[tid >> 6] = m;
  __syncthreads();
  if (tid == 0) {
    m = fmaxf(fmaxf(wred[0], wred[1]), fmaxf(wred[2], wred[3]));
    atomicMax(slot, __float_as_int(m));
  }
}

__device__ __forceinline__ float sc_slot(const int* IS, int slot) {
  unsigned u = (unsigned)__hip_atomic_load((int*)(IS + slot), __ATOMIC_RELAXED,
                                           __HIP_MEMORY_SCOPE_AGENT);
  return fmaxf(__uint_as_float(u) / 127.0f, 1e-8f);
}

// Merged: blocks 0-2 bnfold(bn1,bn2,id); 3..66 w1 amax; 67..194 w2; 195..210 wid; 211..722 x.
__global__ __launch_bounds__(THREADS) void k_pre(
    int* IS, const float* g1, const float* be1, const float* m1, const float* v1, float* wq1,
    float* b1, const float* g2, const float* be2, const float* m2, const float* v2, float* wq2,
    float* b2, const float* gi, const float* bei, const float* mi, const float* vvi, float* wqi,
    float* bi, const float4* w1, const float4* w2, const float4* wid, const float4* x) {
  int b = blockIdx.x;
  int c = threadIdx.x;
  if (b < 3) {
    const float *gamma, *beta, *mean, *var;
    float *wq, *bb;
    if (b == 0) { gamma = g1; beta = be1; mean = m1; var = v1; wq = wq1; bb = b1; }
    else if (b == 1) { gamma = g2; beta = be2; mean = m2; var = v2; wq = wq2; bb = b2; }
    else { gamma = gi; beta = bei; mean = mi; var = vvi; wq = wqi; bb = bi; }
    __shared__ float red[THREADS];
    float ws = gamma[c] * (1.0f / sqrtf(var[c] + 1e-5f));
    red[c] = fabsf(ws);
    __syncthreads();
    for (int s = THREADS / 2; s > 0; s >>= 1) {
      if (c < s) red[c] = fmaxf(red[c], red[c + s]);
      __syncthreads();
    }
    float sws = fmaxf(red[0] / 127.0f, 1e-8f);
    float q = clamp8f(rintf(ws / sws)) * sws;
    wq[c] = q;
    bb[c] = beta[c] - mean[c] * q;
    return;
  }
  b -= 3;
  if (b < 64) { amax_body(w1, 73728, b, 64, IS + 1); return; }
  b -= 64;
  if (b < 128) { amax_body(w2, 147456, b, 128, IS + 2); return; }
  b -= 128;
  if (b < 16) { amax_body(wid, 8192, b, 16, IS + 3); return; }
  b -= 16;
  amax_body(x, 3211264, b, 512, IS + 0);
}

// Merged quantize (r4-proven): blocks [0,1792) qx SCALAR transpose; [1792,1864) qw1;
// [1864,2008) qw2; [2008,2016) qwid.
__global__ __launch_bounds__(THREADS) void k_quant(const float* __restrict__ x,
                                                   int* __restrict__ X8,
                                                   const float* __restrict__ w1f,
                                                   vi4* __restrict__ W1m,
                                                   const float* __restrict__ w2f,
                                                   vi4* __restrict__ W2m,
                                                   const float* __restrict__ widf,
                                                   vi4* __restrict__ Widm,
                                                   const unsigned* __restrict__ ISu) {
  __shared__ signed char tile[56 * 132];
  int b = blockIdx.x;
  int t = threadIdx.x;
  if (b < 1792) {
    float s = sc_from_bits(ISu[0]);
    int h = b % 56, n = b / 56;
    const float* xp = x + ((n * 128) * 56 + h) * 56;
#pragma unroll
    for (int k = 0; k < 28; ++k) {
      int i = t + k * 256;  // < 7168
      int w = i % 56, c = i / 56;
      tile[w * 132 + c] = q8(xp[c * 3136 + w], s);
    }
    __syncthreads();
    int* op = X8 + (n * 56 + h) * 56 * 32;
#pragma unroll
    for (int k = 0; k < 7; ++k) {
      int i = t + k * 256;  // < 1792
      int w = i >> 5, c4 = (i & 31) * 4;
      const signed char* tp = tile + w * 132 + c4;
      op[i] = (int)(unsigned char)tp[0] | ((int)(unsigned char)tp[1] << 8) |
              ((int)(unsigned char)tp[2] << 16) | ((int)(unsigned char)tp[3] << 24);
    }
    return;
  }
  if (b < 1864) {
    int tt = (b - 1792) * THREADS + t;  // < 18432
    float s = sc_from_bits(ISu[1]);
    int lane = tt & 63;
    int cotile = (tt >> 6) & 15;
    int ks = tt >> 10;  // 0..17
    int tap = ks >> 1, kc = ks & 1;
    int kh = tap / 3, kw = tap % 3;
    int co = cotile * 16 + (lane & 15);
    int ci0 = kc * 64 + (lane >> 4) * 16;
    const float* src = w1f + (co * 128 + ci0) * 9 + kh * 3 + kw;
    int r[4];
#pragma unroll
    for (int q = 0; q < 4; ++q) {
      unsigned b0 = (unsigned char)q8(src[(q * 4 + 0) * 9], s);
      unsigned b1 = (unsigned char)q8(src[(q * 4 + 1) * 9], s);
      unsigned b2 = (unsigned char)q8(src[(q * 4 + 2) * 9], s);
      unsigned b3 = (unsigned char)q8(src[(q * 4 + 3) * 9], s);
      r[q] = (int)(b0 | (b1 << 8) | (b2 << 16) | (b3 << 24));
    }
    vi4 v = {r[0], r[1], r[2], r[3]};
    W1m[tt] = v;
    return;
  }
  if (b < 2008) {
    int tt = (b - 1864) * THREADS + t;  // < 36864
    float s = sc_from_bits(ISu[2]);
    int lane = tt & 63;
    int cotile = (tt >> 6) & 15;
    int ks = tt >> 10;  // 0..35
    int tap = ks >> 2, kc = ks & 3;
    int kh = tap / 3, kw = tap % 3;
    int co = cotile * 16 + (lane & 15);
    int ci0 = kc * 64 + (lane >> 4) * 16;
    const float* src = w2f + (co * 256 + ci0) * 9 + kh * 3 + kw;
    int r[4];
#pragma unroll
    for (int q = 0; q < 4; ++q) {
      unsigned b0 = (unsigned char)q8(src[(q * 4 + 0) * 9], s);
      unsigned b1 = (unsigned char)q8(src[(q * 4 + 1) * 9], s);
      unsigned b2 = (unsigned char)q8(src[(q * 4 + 2) * 9], s);
      unsigned b3 = (unsigned char)q8(src[(q * 4 + 3) * 9], s);
      r[q] = (int)(b0 | (b1 << 8) | (b2 << 16) | (b3 << 24));
    }
    vi4 v = {r[0], r[1], r[2], r[3]};
    W2m[tt] = v;
    return;
  }
  {
    int tt = (b - 2008) * THREADS + t;  // < 2048
    float s = sc_from_bits(ISu[3]);
    int lane = tt & 63;
    int cotile = (tt >> 6) & 15;
    int ks = tt >> 10;  // 0..1
    int co = cotile * 16 + (lane & 15);
    int ci0 = ks * 64 + (lane >> 4) * 16;
    const float* src = widf + co * 128 + ci0;
    int r[4];
#pragma unroll
    for (int q = 0; q < 4; ++q) {
      unsigned b0 = (unsigned char)q8(src[q * 4 + 0], s);
      unsigned b1 = (unsigned char)q8(src[q * 4 + 1], s);
      unsigned b2 = (unsigned char)q8(src[q * 4 + 2], s);
      unsigned b3 = (unsigned char)q8(src[q * 4 + 3], s);
      r[q] = (int)(b0 | (b1 << 8) | (b2 << 16) | (b3 << 24));
    }
    vi4 v = {r[0], r[1], r[2], r[3]};
    Widm[tt] = v;
  }
}

#define MFMA_I8(a, b, c) __builtin_amdgcn_mfma_i32_16x16x64_i8(a, b, c, 0, 0, 0)

// quant(h1) -> bn1 -> relu -> quant (scalar form, used in k_cv1 qh1 phase)
__device__ __forceinline__ signed char qact(int v, float sxw, float s_h1, float s_y2, float wq,
                                            float bb) {
  float hf = (float)v * sxw;
  float q = clamp8f(rintf(hf / s_h1));
  float hv = q * s_h1;
  float y = fmaxf(hv * wq + bb, 0.0f);
  float a = fminf(fmaxf(rintf(y / s_y2), -128.0f), 127.0f);
  return (signed char)(int)a;
}

// Fused conv1 stage (r5 version): conv1 3x3 s2 p1 + identity 1x1 s2 + grid-wide scale
// derivation + qh1 => A2 int8, TWO fence-free barriers. Per-channel extrema stay in 8 VGPRs
// across B1; rf evaluated locally (monotone per channel => exact). H1 parked in LDS, never HBM.
// LDS staging XOR-swizzled stride-32 (37.1KB). (256,4): 1024 slots >= 896 co-resident.
__global__ __launch_bounds__(THREADS, 4) void k_cv1(const int* X8, const vi4* __restrict__ W1m,
                                                    const vi4* __restrict__ Widm,
                                                    int* __restrict__ IDI, int* A2i, int* IS,
                                                    const float* __restrict__ wq1,
                                                    const float* __restrict__ b1, float* SC) {
  __shared__ __align__(16) int lds[9280];  // stage 5*58*32; later park h1 [56][130]
  __shared__ int redA[4], redB[4];
  __shared__ float redF[4];
  __shared__ float sSxw, sSh1, sSy2;
  const int tid = threadIdx.x;
  const int bx = blockIdx.x;
  const int n = bx / 28, rr = bx % 28;
  const int hp = rr >> 1, nh = rr & 1;
  const int ho0 = hp * 2;
  vi4 zero = {0, 0, 0, 0};

  // ---- stage 5 input rows, swizzled stride-32 ----
  for (int r = 0; r < 5; ++r) {
    int h = 2 * ho0 - 1 + r;
    int* dst = lds + r * 58 * 32;
    if (h >= 0 && h < 56) {
      const vi4* src = (const vi4*)(X8 + (n * 56 + h) * 56 * 32);
      for (int i4 = tid; i4 < 448; i4 += THREADS) {
        int col = i4 >> 3, e0 = (i4 & 7) * 4;
        int cell = r * 58 + col + 1;
        *(vi4*)(lds + cell * 32 + (e0 ^ ((cell & 7) << 2))) = src[i4];
      }
      if (tid < 32) dst[tid] = 0;
      else if (tid >= 128 && tid < 160) dst[57 * 32 + (tid - 128)] = 0;
    } else {
      for (int i4 = tid; i4 < 464; i4 += THREADS) ((vi4*)dst)[i4] = zero;
    }
  }
  __syncthreads();

  const int lane = tid & 63, wv = tid >> 6;
  const int mw = wv & 1, nw = wv >> 1;
  const int lm = lane & 15, quad = lane >> 4;
  const int woc0 = lm, woc1 = (16 + lm) > 27 ? 27 : (16 + lm);
  const int choff = quad * 4;
  const int ho = ho0 + mw;
  const int obase = ((n * 28 + ho) * 28) * 256;
  const int ctbase = nh * 8 + nw * 4;

#define LDA(row, colp, sub)                                                              \
  (*(const vi4*)(lds + ((row) * 58 + (colp)) * 32 +                                      \
                 ((sub) ^ ((((row) * 58 + (colp)) & 7) << 2))))

  vi4 acc[2][4];
  vi4 bA[4], bB[4];
  vi4 a0A, a1A, a0B, a1B;

  // ---- identity branch first (2 K-steps) ----
#pragma unroll
  for (int mt = 0; mt < 2; ++mt)
#pragma unroll
    for (int ct = 0; ct < 4; ++ct) acc[mt][ct] = zero;
  const vi4* wibase = Widm + ctbase * 64 + lane;
  {
    const int row = 2 * mw + 1;
#pragma unroll
    for (int kc = 0; kc < 2; ++kc) {
      vi4 a0 = LDA(row, 2 * woc0 + 1, kc * 16 + choff);
      vi4 a1 = LDA(row, 2 * woc1 + 1, kc * 16 + choff);
#pragma unroll
      for (int ct = 0; ct < 4; ++ct) {
        vi4 b = wibase[kc * 1024 + ct * 64];
        acc[0][ct] = MFMA_I8(a0, b, acc[0][ct]);
        acc[1][ct] = MFMA_I8(a1, b, acc[1][ct]);
      }
    }
  }
  int am = 0;
#pragma unroll
  for (int ct = 0; ct < 4; ++ct) {
    const int co = (ctbase + ct) * 16 + lm;
#pragma unroll
    for (int mt = 0; mt < 2; ++mt)
#pragma unroll
      for (int r = 0; r < 4; ++r) {
        int wo = mt * 16 + quad * 4 + r;
        if (wo < 28) {
          int v = acc[mt][ct][r];
          IDI[obase + wo * 256 + co] = v;  // plain store: consumed by k_tail after boundary
          am = max(am, v < 0 ? -v : v);
        }
      }
  }
#pragma unroll
  for (int k = 32; k >= 1; k >>= 1) am = max(am, __shfl_xor(am, k));
  if (lane == 0) redA[wv] = am;

  // ---- main 3x3 conv, 18 K-steps, ping-pong ----
#pragma unroll
  for (int mt = 0; mt < 2; ++mt)
#pragma unroll
    for (int ct = 0; ct < 4; ++ct) acc[mt][ct] = zero;
  const vi4* wbase = W1m + ctbase * 64 + lane;
#pragma unroll
  for (int ct = 0; ct < 4; ++ct) bA[ct] = wbase[ct * 64];
  {
    a0A = LDA(2 * mw, 2 * woc0, choff);
    a1A = LDA(2 * mw, 2 * woc1, choff);
  }
#pragma unroll 1
  for (int ks = 0; ks < 18; ks += 2) {
    {
      const int ksn = ks + 1;
      const int khn = (ksn >= 6) + (ksn >= 12);
      const int t2 = ksn - khn * 6;
      const int kwn = t2 >> 1, kcn = t2 & 1;
#pragma unroll
      for (int ct = 0; ct < 4; ++ct) bB[ct] = wbase[ksn * 1024 + ct * 64];
      const int row = 2 * mw + khn;
      a0B = LDA(row, 2 * woc0 + kwn, kcn * 16 + choff);
      a1B = LDA(row, 2 * woc1 + kwn, kcn * 16 + choff);
    }
#pragma unroll
    for (int ct = 0; ct < 4; ++ct) {
      acc[0][ct] = MFMA_I8(a0A, bA[ct], acc[0][ct]);
      acc[1][ct] = MFMA_I8(a1A, bA[ct], acc[1][ct]);
    }
    if (ks + 2 < 18) {
      const int ksn = ks + 2;
      const int khn = (ksn >= 6) + (ksn >= 12);
      const int t2 = ksn - khn * 6;
      const int kwn = t2 >> 1, kcn = t2 & 1;
#pragma unroll
      for (int ct = 0; ct < 4; ++ct) bA[ct] = wbase[ksn * 1024 + ct * 64];
      const int row = 2 * mw + khn;
      a0A = LDA(row, 2 * woc0 + kwn, kcn * 16 + choff);
      a1A = LDA(row, 2 * woc1 + kwn, kcn * 16 + choff);
    }
#pragma unroll
    for (int ct = 0; ct < 4; ++ct) {
      acc[0][ct] = MFMA_I8(a0B, bB[ct], acc[0][ct]);
      acc[1][ct] = MFMA_I8(a1B, bB[ct], acc[1][ct]);
    }
  }

  // ---- per-channel extrema in REGISTERS + block absmax(h1) ----
  int vmx[4], vmn[4];
  int am1 = 0;
#pragma unroll
  for (int ct = 0; ct < 4; ++ct) {
    int vmax = INT_MIN, vmin = INT_MAX;
#pragma unroll
    for (int mt = 0; mt < 2; ++mt)
#pragma unroll
      for (int r = 0; r < 4; ++r) {
        int wo = mt * 16 + quad * 4 + r;
        if (wo < 28) {
          int v = acc[mt][ct][r];
          vmax = max(vmax, v);
          vmin = min(vmin, v);
        }
      }
    vmax = max(vmax, __shfl_xor(vmax, 16));
    vmax = max(vmax, __shfl_xor(vmax, 32));
    vmin = min(vmin, __shfl_xor(vmin, 16));
    vmin = min(vmin, __shfl_xor(vmin, 32));
    vmx[ct] = vmax;
    vmn[ct] = vmin;
    am1 = max(am1, max(vmax < 0 ? -vmax : vmax, vmin < 0 ? -vmin : vmin));
  }
#pragma unroll
  for (int k = 8; k >= 1; k >>= 1) am1 = max(am1, __shfl_xor(am1, k));
  if (lane == 0) redB[wv] = am1;

  __syncthreads();  // staging reads done -> park may overwrite; redA/redB ready
  // ---- park h1 into LDS [sp=mw*28+wo][130] ----
#pragma unroll
  for (int ct = 0; ct < 4; ++ct) {
    const int cl = (nw * 4 + ct) * 16 + lm;
#pragma unroll
    for (int mt = 0; mt < 2; ++mt)
#pragma unroll
      for (int r = 0; r < 4; ++r) {
        int wo = mt * 16 + quad * 4 + r;
        if (wo < 28) lds[(mw * 28 + wo) * 130 + cl] = acc[mt][ct][r];
      }
  }
  if (tid == 0) {
    atomicMax(IS + 5, max(max(redA[0], redA[1]), max(redA[2], redA[3])));
    atomicMax(IS + 4, max(max(redB[0], redB[1]), max(redB[2], redB[3])));
    gbar(IS, 288, bx, 112);  // B1: mh1 + id amax global
    float sx = sc_slot(IS, 0);
    float sw1 = sc_slot(IS, 1);
    int mh1 = __hip_atomic_load(IS + 4, __ATOMIC_RELAXED, __HIP_MEMORY_SCOPE_AGENT);
    sSxw = sx * sw1;
    sSh1 = fmaxf(sSxw * (float)mh1 / 127.0f, 1e-8f);
  }
  __syncthreads();

  // ---- local rf eval at own per-channel extrema (monotone => exact) ----
  {
    const float sxw = sSxw, s_h1 = sSh1;
    float ym = 0.0f;
#pragma unroll
    for (int ct = 0; ct < 4; ++ct) {
      const int co = (ctbase + ct) * 16 + lm;
      float wq = wq1[co], bbc = b1[co];
      float q1 = clamp8f(rintf((float)vmx[ct] * sxw / s_h1));
      float q0 = clamp8f(rintf((float)vmn[ct] * sxw / s_h1));
      float y1 = fmaxf(q1 * s_h1 * wq + bbc, 0.0f);
      float y0 = fmaxf(q0 * s_h1 * wq + bbc, 0.0f);
      ym = fmaxf(ym, fmaxf(y1, y0));
    }
#pragma unroll
    for (int k = 8; k >= 1; k >>= 1) ym = fmaxf(ym, __shfl_xor(ym, k));
    if (lane == 0) redF[wv] = ym;
  }
  __syncthreads();
  if (tid == 0) {
    atomicMax(IS + 7, __float_as_int(fmaxf(fmaxf(redF[0], redF[1]), fmaxf(redF[2], redF[3]))));
    gbar(IS, 448, bx, 112);  // B2: rf global (short gap after B1 -> tiny skew)
    int mrf = __hip_atomic_load(IS + 7, __ATOMIC_RELAXED, __HIP_MEMORY_SCOPE_AGENT);
    float s_y2 = fmaxf(__int_as_float(mrf) / 127.0f, 1e-8f);
    sSy2 = s_y2;
    if (bx == 0) {
      int mid = __hip_atomic_load(IS + 5, __ATOMIC_RELAXED, __HIP_MEMORY_SCOPE_AGENT);
      float sx = sc_slot(IS, 0);
      float swid = sc_slot(IS, 3);
      SC[9] = s_y2;  // plain stores: kernel-end flush -> visible to k_tail
      SC[10] = fmaxf(sx * swid * (float)mid / 127.0f, 1e-8f);
    }
  }
  __syncthreads();

  // ---- qh1 from parked LDS -> A2 int8 (NHWC, own channel-half), coalesced int writes ----
  {
    const float sxw = sSxw, s_h1 = sSh1, s_y2 = sSy2;
#pragma unroll
    for (int k = 0; k < 7; ++k) {
      int i = tid + k * 256;  // < 1792
      int sp = i >> 5, c4i = i & 31;
      int mwp = sp >= 28 ? 1 : 0;
      int wo = sp - mwp * 28;
      int c0 = nh * 128 + c4i * 4;
      const int* pk = lds + sp * 130 + c4i * 4;
      unsigned r0 = (unsigned char)qact(pk[0], sxw, s_h1, s_y2, wq1[c0], b1[c0]);
      unsigned r1 = (unsigned char)qact(pk[1], sxw, s_h1, s_y2, wq1[c0 + 1], b1[c0 + 1]);
      unsigned r2 = (unsigned char)qact(pk[2], sxw, s_h1, s_y2, wq1[c0 + 2], b1[c0 + 2]);
      unsigned r3 = (unsigned char)qact(pk[3], sxw, s_h1, s_y2, wq1[c0 + 3], b1[c0 + 3]);
      A2i[((n * 28 + ho0 + mwp) * 28 + wo) * 64 + nh * 32 + c4i] =
          (int)(r0 | (r1 << 8) | (r2 << 16) | (r3 << 24));
    }
  }
#undef LDA
}

// ---- residual sum math ----
struct SumParams {
  float sxw2, s_h2, sxwid, s_idq;
};
__device__ __forceinline__ float sum_val(int v2, int vi, const SumParams& P, float wq2c, float b2c,
                                         float wqidc, float bidc) {
  float q2 = clamp8f(rintf((float)v2 * P.sxw2 / P.s_h2));
  float z = (q2 * P.s_h2) * wq2c + b2c;
  float qi = clamp8f(rintf((float)vi * P.sxwid / P.s_idq));
  float zi = (qi * P.s_idq) * wqidc + bidc;
  return z + zi;
}
__device__ __forceinline__ SumParams make_params2(const float* SC, const unsigned* ISu, int mh2) {
  SumParams P;
  float sx = sc_from_bits(ISu[0]);
  float sw2 = sc_from_bits(ISu[2]);
  float swid = sc_from_bits(ISu[3]);
  float s_y2 = SC[9];
  P.s_idq = SC[10];
  P.sxw2 = s_y2 * sw2;
  P.s_h2 = fmaxf(P.sxw2 * (float)mh2 / 127.0f, 1e-8f);
  P.sxwid = sx * swid;
  return P;
}

// Fused tail (r3-proven, ~67us): conv2 3x3 s1 p1 (Cin=256) + residual absmax + requant + NCHW out.
// Fence-free grid barriers at bases 608/768. H2 never hits HBM.
__global__ __launch_bounds__(THREADS, 4) void k_tail(const int* __restrict__ A2,
                                                     const vi4* __restrict__ W2m,
                                                     const int* __restrict__ IDI,
                                                     const float* SC, int* IS,
                                                     const float* __restrict__ wq2,
                                                     const float* __restrict__ b2,
                                                     const float* __restrict__ wqid,
                                                     const float* __restrict__ bidp,
                                                     float* __restrict__ out) {
  __shared__ __align__(16) int lds[4 * 30 * 68];  // 32640B; reused for sums [128][57] f32
  __shared__ int redA[4];
  __shared__ float redF[4];
  __shared__ int sMh2;
  __shared__ float sOutS;
  const int tid = threadIdx.x;
  const int bx = blockIdx.x;
  const int n = bx / 28, rr = bx % 28;
  const int hp = rr >> 1, nh = rr & 1;
  const int ho0 = hp * 2;
  vi4 zero = {0, 0, 0, 0};

  for (int r = 0; r < 4; ++r) {
    int h = ho0 - 1 + r;
    int* dst = lds + r * 30 * 68;
    if (h >= 0 && h < 28) {
      const vi4* src = (const vi4*)(A2 + (n * 28 + h) * 28 * 64);
      for (int i4 = tid; i4 < 448; i4 += THREADS) {
        int col = i4 >> 4, c = (i4 & 15) * 4;
        *(vi4*)(dst + (col + 1) * 68 + c) = src[i4];
      }
      if (tid < 64) dst[tid] = 0;
      else if (tid >= 128 && tid < 192) dst[29 * 68 + (tid - 128)] = 0;
    } else {
      for (int i4 = tid; i4 < 510; i4 += THREADS) ((vi4*)dst)[i4] = zero;
    }
  }
  __syncthreads();

  const int lane = tid & 63, wv = tid >> 6;
  const int mw = wv & 1, nw = wv >> 1;
  const int lm = lane & 15, quad = lane >> 4;
  const int woc0 = lm, woc1 = (16 + lm) > 27 ? 27 : (16 + lm);
  const int choff = quad * 4;
  const int ctbase = nh * 8 + nw * 4;

  vi4 acc[2][4];
  vi4 bA[4], bB[4];
  vi4 a0A, a1A, a0B, a1B;
#pragma unroll
  for (int mt = 0; mt < 2; ++mt)
#pragma unroll
    for (int ct = 0; ct < 4; ++ct) acc[mt][ct] = zero;

  const vi4* wbase = W2m + ctbase * 64 + lane;
#pragma unroll
  for (int ct = 0; ct < 4; ++ct) bA[ct] = wbase[ct * 64];
  {
    const int ro = mw * 30;  // ks=0
    a0A = *(const vi4*)(lds + (ro + woc0) * 68 + choff);
    a1A = *(const vi4*)(lds + (ro + woc1) * 68 + choff);
  }
#pragma unroll 1
  for (int ks = 0; ks < 36; ks += 2) {
    {
      const int ksn = ks + 1;
      const int khn = (ksn >= 12) + (ksn >= 24);
      const int t2 = ksn - khn * 12;
      const int kwn = t2 >> 2, kcn = t2 & 3;
#pragma unroll
      for (int ct = 0; ct < 4; ++ct) bB[ct] = wbase[ksn * 1024 + ct * 64];
      const int ro = (mw + khn) * 30;
      a0B = *(const vi4*)(lds + (ro + woc0 + kwn) * 68 + kcn * 16 + choff);
      a1B = *(const vi4*)(lds + (ro + woc1 + kwn) * 68 + kcn * 16 + choff);
    }
#pragma unroll
    for (int ct = 0; ct < 4; ++ct) {
      acc[0][ct] = MFMA_I8(a0A, bA[ct], acc[0][ct]);
      acc[1][ct] = MFMA_I8(a1A, bA[ct], acc[1][ct]);
    }
    if (ks + 2 < 36) {
      const int ksn = ks + 2;
      const int khn = (ksn >= 12) + (ksn >= 24);
      const int t2 = ksn - khn * 12;
      const int kwn = t2 >> 2, kcn = t2 & 3;
#pragma unroll
      for (int ct = 0; ct < 4; ++ct) bA[ct] = wbase[ksn * 1024 + ct * 64];
      const int ro = (mw + khn) * 30;
      a0A = *(const vi4*)(lds + (ro + woc0 + kwn) * 68 + kcn * 16 + choff);
      a1A = *(const vi4*)(lds + (ro + woc1 + kwn) * 68 + kcn * 16 + choff);
    }
#pragma unroll
    for (int ct = 0; ct < 4; ++ct) {
      acc[0][ct] = MFMA_I8(a0B, bB[ct], acc[0][ct]);
      acc[1][ct] = MFMA_I8(a1B, bB[ct], acc[1][ct]);
    }
  }

  // ---- block max|h2| straight from acc (H2 never stored) ----
  int am = 0;
#pragma unroll
  for (int ct = 0; ct < 4; ++ct)
#pragma unroll
    for (int mt = 0; mt < 2; ++mt)
#pragma unroll
      for (int r = 0; r < 4; ++r) {
        int wo = mt * 16 + quad * 4 + r;
        if (wo < 28) {
          int v = acc[mt][ct][r];
          am = max(am, v < 0 ? -v : v);
        }
      }
#pragma unroll
  for (int k = 32; k >= 1; k >>= 1) am = max(am, __shfl_xor(am, k));
  if (lane == 0) redA[wv] = am;
  __syncthreads();
  if (tid == 0) {
    int a = max(max(redA[0], redA[1]), max(redA[2], redA[3]));
    atomicMax(IS + 6, a);  // device RMW (coherence point)
  }

  // ---- stage this block's IDI half into LDS, transposed [cl][sp] (pad 57) ----
  int* sumsi = lds;
  float* sums = (float*)lds;
  const int ib = ((n * 28 + ho0) * 28) * 256 + nh * 128;
#pragma unroll
  for (int k = 0; k < 28; ++k) {
    int idx = tid + k * 256;            // 0..7167
    int cl = idx & 127, sp = idx >> 7;  // sp = hl*28+wo
    sumsi[cl * 57 + sp] = IDI[ib + sp * 256 + cl];
  }
  __syncthreads();
  if (tid == 0) {
    gbar(IS, 608, bx, 112);  // B: max|h2| global
    sMh2 = __hip_atomic_load(IS + 6, __ATOMIC_RELAXED, __HIP_MEMORY_SCOPE_SYSTEM);
  }
  __syncthreads();
  const SumParams P = make_params2(SC, (const unsigned*)IS, sMh2);

  // ---- RMW owned slots: sum = z + zi; track |sum| ----
  float fm = 0.0f;
#pragma unroll
  for (int ct = 0; ct < 4; ++ct) {
    const int co = (ctbase + ct) * 16 + lm;
    const int cl = co - nh * 128;
    float w2c = wq2[co], b2c = b2[co], wic = wqid[co], bic = bidp[co];
#pragma unroll
    for (int mt = 0; mt < 2; ++mt)
#pragma unroll
      for (int r = 0; r < 4; ++r) {
        int wo = mt * 16 + quad * 4 + r;
        if (wo < 28) {
          int slot = cl * 57 + mw * 28 + wo;
          float sv = sum_val(acc[mt][ct][r], sumsi[slot], P, w2c, b2c, wic, bic);
          sums[slot] = sv;
          fm = fmaxf(fm, fabsf(sv));
        }
      }
  }
#pragma unroll
  for (int k = 32; k >= 1; k >>= 1) fm = fmaxf(fm, __shfl_xor(fm, k));
  if (lane == 0) redF[wv] = fm;
  __syncthreads();
  if (tid == 0) {
    float a = fmaxf(fmaxf(redF[0], redF[1]), fmaxf(redF[2], redF[3]));
    atomicMax(IS + 11, __float_as_int(a));
    gbar(IS, 768, bx, 112);  // B: max|sum| global
    int mb = __hip_atomic_load(IS + 11, __ATOMIC_RELAXED, __HIP_MEMORY_SCOPE_SYSTEM);
    sOutS = fmaxf(__int_as_float(mb) / 127.0f, 1e-8f);
  }
  __syncthreads();
  const float out_s = sOutS;

  // ---- requant + relu, NCHW write ----
  float* ob = out + n * 200704 + (nh * 128) * 784 + ho0 * 28;
#pragma unroll
  for (int k = 0; k < 28; ++k) {
    int idx = tid + k * 256;
    int cl = idx / 56, rem = idx % 56;
    float sv = sums[cl * 57 + rem];
    float q = clamp8f(rintf(sv / out_s));
    ob[cl * 784 + rem] = q > 0.0f ? q * out_s : 0.0f;
  }
  if (bx == 0 && tid == 0) out[6422528] = out_s;
}

extern "C" void kernel_launch(void* const* d_in, const int* in_sizes, int n_in, void* d_out,
                              int out_size, void* d_ws, size_t ws_size, hipStream_t stream) {
  (void)in_sizes; (void)n_in; (void)out_size; (void)ws_size;
  const float* x = (const float*)d_in[0];
  const float* w1 = (const float*)d_in[1];
  const float* w2 = (const float*)d_in[2];
  const float* wid = (const float*)d_in[3];
  const float* bn1g = (const float*)d_in[4];
  const float* bn1b = (const float*)d_in[5];
  const float* bn1m = (const float*)d_in[6];
  const float* bn1v = (const float*)d_in[7];
  const float* bn2g = (const float*)d_in[8];
  const float* bn2b = (const float*)d_in[9];
  const float* bn2m = (const float*)d_in[10];
  const float* bn2v = (const float*)d_in[11];
  const float* idg = (const float*)d_in[12];
  const float* idb = (const float*)d_in[13];
  const float* idm = (const float*)d_in[14];
  const float* idv = (const float*)d_in[15];

  char* ws = (char*)d_ws;
  float* SC = (float*)ws;
  int* IS = (int*)ws;
  unsigned* ISu = (unsigned*)ws;
  // barrier counters occupy IS[128..1024); per-channel tables after:
  float* wq1 = (float*)(ws + 4096);
  float* b1 = (float*)(ws + 5120);
  float* wq2 = (float*)(ws + 6144);
  float* b2 = (float*)(ws + 7168);
  float* wqid = (float*)(ws + 8192);
  float* bid = (float*)(ws + 9216);
  char* X8 = ws + 16384;  // NHWC int8; A2 overlays (all X8 reads complete before qh1 writes)
  char* A2 = X8;
  char* W1m = X8 + 12845056;
  char* W2m = W1m + 294912;
  char* Widm = W2m + 589824;
  int* IDI = (int*)(Widm + 32768);
  float* out = (float*)d_out;

  // re-arm all grid-barrier counters (graph-capturable stream memset)
  hipMemsetAsync(ws + 512, 0, 3584, stream);  // IS[128..1024)

  k_pre<<<723, THREADS, 0, stream>>>(IS, bn1g, bn1b, bn1m, bn1v, wq1, b1, bn2g, bn2b, bn2m, bn2v,
                                     wq2, b2, idg, idb, idm, idv, wqid, bid, (const float4*)w1,
                                     (const float4*)w2, (const float4*)wid, (const float4*)x);
  k_quant<<<2016, THREADS, 0, stream>>>(x, (int*)X8, w1, (vi4*)W1m, w2, (vi4*)W2m, wid,
                                        (vi4*)Widm, ISu);
  k_cv1<<<GRID_BLOCKS, THREADS, 0, stream>>>((const int*)X8, (const vi4*)W1m, (const vi4*)Widm,
                                             IDI, (int*)A2, IS, wq1, b1, SC);
  k_tail<<<GRID_BLOCKS, THREADS, 0, stream>>>((const int*)A2, (const vi4*)W2m, (const int*)IDI, SC,
                                              IS, wq2, b2, wqid, bid, out);
}

// Round 9
// 259.394 us; speedup vs baseline: 1.2126x; 1.0121x over previous
//
#include <hip/hip_runtime.h>
#include <limits.h>

#define THREADS 256
#define GRID_BLOCKS 896

typedef int vi4 __attribute__((ext_vector_type(4)));

__device__ __forceinline__ float clamp8f(float q) { return fminf(fmaxf(q, -128.0f), 127.0f); }
__device__ __forceinline__ float sc_from_bits(unsigned b) {
  return fmaxf(__uint_as_float(b) / 127.0f, 1e-8f);
}
__device__ __forceinline__ signed char q8(float v, float s) {
  return (signed char)(int)clamp8f(rintf(v / s));
}

// Scalar slots: [0] amax_x [1] amax_w1 [2] amax_w2 [3] amax_wid
// [4] maxabs_h1 [5] maxabs_id [6] maxabs_h2 [7] max_y2(rf bits) [9] s_y2 [10] s_idq [11] amax_sum
// Grid barriers zeroed by k_pre block 0 (plain stores, kernel-end flush; r4-proven — r9 lesson
// candidate: hipMemsetAsync in a captured graph becomes a small SDMA node with ~10+us fixed
// overhead; present in every slow round r5-r8, absent in fast r3/r4).
//   bases: k_cv1 288,448; k_tail 608,768. Per base B: subs B+s*16 (s<8), root B+128, flag B+144.
// All value slots use SIGNED atomicMax; 0xAA poison is negative -> no init pass.
// r5/r7 lessons: grid-barrier fronts force VGPR caps that kill load pipelining. Front stays as
// two UNCAPPED kernels.

__device__ __forceinline__ void gbar(int* IS, int base, int bx, int subTgt) {
  // fence-free barrier (r3-proven): relaxed hierarchical arrive + relaxed system poll.
  asm volatile("s_waitcnt vmcnt(0)" ::: "memory");  // caller tid0's own RMWs
  int old = __hip_atomic_fetch_add(IS + base + (bx & 7) * 16, 1, __ATOMIC_RELAXED,
                                   __HIP_MEMORY_SCOPE_AGENT);
  if (old == subTgt - 1) {
    int r = __hip_atomic_fetch_add(IS + base + 128, 1, __ATOMIC_RELAXED, __HIP_MEMORY_SCOPE_AGENT);
    if (r == 7)
      __hip_atomic_fetch_add(IS + base + 144, 1, __ATOMIC_RELAXED, __HIP_MEMORY_SCOPE_AGENT);
  }
  while (__hip_atomic_load(IS + base + 144, __ATOMIC_RELAXED, __HIP_MEMORY_SCOPE_SYSTEM) == 0)
    __builtin_amdgcn_s_sleep(2);
}

__device__ __forceinline__ void amax_body(const float4* __restrict__ p, int n4, int bid,
                                          int nblocks, int* __restrict__ slot) {
  const int tid = threadIdx.x;
  const int stride = nblocks * THREADS;
  float m = 0.0f;
  int i = bid * THREADS + tid;
  for (; i + 3 * stride < n4; i += 4 * stride) {
    float4 v0 = p[i];
    float4 v1 = p[i + stride];
    float4 v2 = p[i + 2 * stride];
    float4 v3 = p[i + 3 * stride];
    float m0 = fmaxf(fmaxf(fabsf(v0.x), fabsf(v0.y)), fmaxf(fabsf(v0.z), fabsf(v0.w)));
    float m1 = fmaxf(fmaxf(fabsf(v1.x), fabsf(v1.y)), fmaxf(fabsf(v1.z), fabsf(v1.w)));
    float m2 = fmaxf(fmaxf(fabsf(v2.x), fabsf(v2.y)), fmaxf(fabsf(v2.z), fabsf(v2.w)));
    float m3 = fmaxf(fmaxf(fabsf(v3.x), fabsf(v3.y)), fmaxf(fabsf(v3.z), fabsf(v3.w)));
    m = fmaxf(m, fmaxf(fmaxf(m0, m1), fmaxf(m2, m3)));
  }
  for (; i < n4; i += stride) {
    float4 v = p[i];
    m = fmaxf(m, fmaxf(fmaxf(fabsf(v.x), fabsf(v.y)), fmaxf(fabsf(v.z), fabsf(v.w))));
  }
#pragma unroll
  for (int k = 32; k >= 1; k >>= 1) m = fmaxf(m, __shfl_xor(m, k));
  __shared__ float wred[4];
  if ((tid & 63) == 0) wred[tid >> 6] = m;
  __syncthreads();
  if (tid == 0) {
    m = fmaxf(fmaxf(wred[0], wred[1]), fmaxf(wred[2], wred[3]));
    atomicMax(slot, __float_as_int(m));
  }
}

__device__ __forceinline__ float sc_slot(const int* IS, int slot) {
  unsigned u = (unsigned)__hip_atomic_load((int*)(IS + slot), __ATOMIC_RELAXED,
                                           __HIP_MEMORY_SCOPE_AGENT);
  return fmaxf(__uint_as_float(u) / 127.0f, 1e-8f);
}

// Merged: blocks 0-2 bnfold(bn1,bn2,id); 3..66 w1 amax; 67..194 w2; 195..210 wid; 211..722 x.
// Block 0 also zeroes all grid-barrier counters IS[128..1024) (replaces hipMemsetAsync).
__global__ __launch_bounds__(THREADS) void k_pre(
    int* IS, const float* g1, const float* be1, const float* m1, const float* v1, float* wq1,
    float* b1, const float* g2, const float* be2, const float* m2, const float* v2, float* wq2,
    float* b2, const float* gi, const float* bei, const float* mi, const float* vvi, float* wqi,
    float* bi, const float4* w1, const float4* w2, const float4* wid, const float4* x) {
  int b = blockIdx.x;
  int c = threadIdx.x;
  if (b < 3) {
    if (b == 0) {
      IS[128 + c] = 0;
      IS[384 + c] = 0;
      IS[640 + c] = 0;
      if (c < 128) IS[896 + c] = 0;
    }
    const float *gamma, *beta, *mean, *var;
    float *wq, *bb;
    if (b == 0) { gamma = g1; beta = be1; mean = m1; var = v1; wq = wq1; bb = b1; }
    else if (b == 1) { gamma = g2; beta = be2; mean = m2; var = v2; wq = wq2; bb = b2; }
    else { gamma = gi; beta = bei; mean = mi; var = vvi; wq = wqi; bb = bi; }
    __shared__ float red[THREADS];
    float ws = gamma[c] * (1.0f / sqrtf(var[c] + 1e-5f));
    red[c] = fabsf(ws);
    __syncthreads();
    for (int s = THREADS / 2; s > 0; s >>= 1) {
      if (c < s) red[c] = fmaxf(red[c], red[c + s]);
      __syncthreads();
    }
    float sws = fmaxf(red[0] / 127.0f, 1e-8f);
    float q = clamp8f(rintf(ws / sws)) * sws;
    wq[c] = q;
    bb[c] = beta[c] - mean[c] * q;
    return;
  }
  b -= 3;
  if (b < 64) { amax_body(w1, 73728, b, 64, IS + 1); return; }
  b -= 64;
  if (b < 128) { amax_body(w2, 147456, b, 128, IS + 2); return; }
  b -= 128;
  if (b < 16) { amax_body(wid, 8192, b, 16, IS + 3); return; }
  b -= 16;
  amax_body(x, 3211264, b, 512, IS + 0);
}

// Merged quantize (r4-proven): blocks [0,1792) qx SCALAR transpose; [1792,1864) qw1;
// [1864,2008) qw2; [2008,2016) qwid.
__global__ __launch_bounds__(THREADS) void k_quant(const float* __restrict__ x,
                                                   int* __restrict__ X8,
                                                   const float* __restrict__ w1f,
                                                   vi4* __restrict__ W1m,
                                                   const float* __restrict__ w2f,
                                                   vi4* __restrict__ W2m,
                                                   const float* __restrict__ widf,
                                                   vi4* __restrict__ Widm,
                                                   const unsigned* __restrict__ ISu) {
  __shared__ signed char tile[56 * 132];
  int b = blockIdx.x;
  int t = threadIdx.x;
  if (b < 1792) {
    float s = sc_from_bits(ISu[0]);
    int h = b % 56, n = b / 56;
    const float* xp = x + ((n * 128) * 56 + h) * 56;
#pragma unroll
    for (int k = 0; k < 28; ++k) {
      int i = t + k * 256;  // < 7168
      int w = i % 56, c = i / 56;
      tile[w * 132 + c] = q8(xp[c * 3136 + w], s);
    }
    __syncthreads();
    int* op = X8 + (n * 56 + h) * 56 * 32;
#pragma unroll
    for (int k = 0; k < 7; ++k) {
      int i = t + k * 256;  // < 1792
      int w = i >> 5, c4 = (i & 31) * 4;
      const signed char* tp = tile + w * 132 + c4;
      op[i] = (int)(unsigned char)tp[0] | ((int)(unsigned char)tp[1] << 8) |
              ((int)(unsigned char)tp[2] << 16) | ((int)(unsigned char)tp[3] << 24);
    }
    return;
  }
  if (b < 1864) {
    int tt = (b - 1792) * THREADS + t;  // < 18432
    float s = sc_from_bits(ISu[1]);
    int lane = tt & 63;
    int cotile = (tt >> 6) & 15;
    int ks = tt >> 10;  // 0..17
    int tap = ks >> 1, kc = ks & 1;
    int kh = tap / 3, kw = tap % 3;
    int co = cotile * 16 + (lane & 15);
    int ci0 = kc * 64 + (lane >> 4) * 16;
    const float* src = w1f + (co * 128 + ci0) * 9 + kh * 3 + kw;
    int r[4];
#pragma unroll
    for (int q = 0; q < 4; ++q) {
      unsigned b0 = (unsigned char)q8(src[(q * 4 + 0) * 9], s);
      unsigned b1 = (unsigned char)q8(src[(q * 4 + 1) * 9], s);
      unsigned b2 = (unsigned char)q8(src[(q * 4 + 2) * 9], s);
      unsigned b3 = (unsigned char)q8(src[(q * 4 + 3) * 9], s);
      r[q] = (int)(b0 | (b1 << 8) | (b2 << 16) | (b3 << 24));
    }
    vi4 v = {r[0], r[1], r[2], r[3]};
    W1m[tt] = v;
    return;
  }
  if (b < 2008) {
    int tt = (b - 1864) * THREADS + t;  // < 36864
    float s = sc_from_bits(ISu[2]);
    int lane = tt & 63;
    int cotile = (tt >> 6) & 15;
    int ks = tt >> 10;  // 0..35
    int tap = ks >> 2, kc = ks & 3;
    int kh = tap / 3, kw = tap % 3;
    int co = cotile * 16 + (lane & 15);
    int ci0 = kc * 64 + (lane >> 4) * 16;
    const float* src = w2f + (co * 256 + ci0) * 9 + kh * 3 + kw;
    int r[4];
#pragma unroll
    for (int q = 0; q < 4; ++q) {
      unsigned b0 = (unsigned char)q8(src[(q * 4 + 0) * 9], s);
      unsigned b1 = (unsigned char)q8(src[(q * 4 + 1) * 9], s);
      unsigned b2 = (unsigned char)q8(src[(q * 4 + 2) * 9], s);
      unsigned b3 = (unsigned char)q8(src[(q * 4 + 3) * 9], s);
      r[q] = (int)(b0 | (b1 << 8) | (b2 << 16) | (b3 << 24));
    }
    vi4 v = {r[0], r[1], r[2], r[3]};
    W2m[tt] = v;
    return;
  }
  {
    int tt = (b - 2008) * THREADS + t;  // < 2048
    float s = sc_from_bits(ISu[3]);
    int lane = tt & 63;
    int cotile = (tt >> 6) & 15;
    int ks = tt >> 10;  // 0..1
    int co = cotile * 16 + (lane & 15);
    int ci0 = ks * 64 + (lane >> 4) * 16;
    const float* src = widf + co * 128 + ci0;
    int r[4];
#pragma unroll
    for (int q = 0; q < 4; ++q) {
      unsigned b0 = (unsigned char)q8(src[q * 4 + 0], s);
      unsigned b1 = (unsigned char)q8(src[q * 4 + 1], s);
      unsigned b2 = (unsigned char)q8(src[q * 4 + 2], s);
      unsigned b3 = (unsigned char)q8(src[q * 4 + 3], s);
      r[q] = (int)(b0 | (b1 << 8) | (b2 << 16) | (b3 << 24));
    }
    vi4 v = {r[0], r[1], r[2], r[3]};
    Widm[tt] = v;
  }
}

#define MFMA_I8(a, b, c) __builtin_amdgcn_mfma_i32_16x16x64_i8(a, b, c, 0, 0, 0)

// quant(h1) -> bn1 -> relu -> quant (scalar form, used in k_cv1 qh1 phase)
__device__ __forceinline__ signed char qact(int v, float sxw, float s_h1, float s_y2, float wq,
                                            float bb) {
  float hf = (float)v * sxw;
  float q = clamp8f(rintf(hf / s_h1));
  float hv = q * s_h1;
  float y = fmaxf(hv * wq + bb, 0.0f);
  float a = fminf(fmaxf(rintf(y / s_y2), -128.0f), 127.0f);
  return (signed char)(int)a;
}

// Fused conv1 stage (r5 version): conv1 3x3 s2 p1 + identity 1x1 s2 + grid-wide scale
// derivation + qh1 => A2 int8, TWO fence-free barriers. Per-channel extrema stay in 8 VGPRs
// across B1; rf evaluated locally (monotone per channel => exact). H1 parked in LDS, never HBM.
// LDS staging XOR-swizzled stride-32 (37.1KB). (256,4): 1024 slots >= 896 co-resident.
__global__ __launch_bounds__(THREADS, 4) void k_cv1(const int* X8, const vi4* __restrict__ W1m,
                                                    const vi4* __restrict__ Widm,
                                                    int* __restrict__ IDI, int* A2i, int* IS,
                                                    const float* __restrict__ wq1,
                                                    const float* __restrict__ b1, float* SC) {
  __shared__ __align__(16) int lds[9280];  // stage 5*58*32; later park h1 [56][130]
  __shared__ int redA[4], redB[4];
  __shared__ float redF[4];
  __shared__ float sSxw, sSh1, sSy2;
  const int tid = threadIdx.x;
  const int bx = blockIdx.x;
  const int n = bx / 28, rr = bx % 28;
  const int hp = rr >> 1, nh = rr & 1;
  const int ho0 = hp * 2;
  vi4 zero = {0, 0, 0, 0};

  // ---- stage 5 input rows, swizzled stride-32 ----
  for (int r = 0; r < 5; ++r) {
    int h = 2 * ho0 - 1 + r;
    int* dst = lds + r * 58 * 32;
    if (h >= 0 && h < 56) {
      const vi4* src = (const vi4*)(X8 + (n * 56 + h) * 56 * 32);
      for (int i4 = tid; i4 < 448; i4 += THREADS) {
        int col = i4 >> 3, e0 = (i4 & 7) * 4;
        int cell = r * 58 + col + 1;
        *(vi4*)(lds + cell * 32 + (e0 ^ ((cell & 7) << 2))) = src[i4];
      }
      if (tid < 32) dst[tid] = 0;
      else if (tid >= 128 && tid < 160) dst[57 * 32 + (tid - 128)] = 0;
    } else {
      for (int i4 = tid; i4 < 464; i4 += THREADS) ((vi4*)dst)[i4] = zero;
    }
  }
  __syncthreads();

  const int lane = tid & 63, wv = tid >> 6;
  const int mw = wv & 1, nw = wv >> 1;
  const int lm = lane & 15, quad = lane >> 4;
  const int woc0 = lm, woc1 = (16 + lm) > 27 ? 27 : (16 + lm);
  const int choff = quad * 4;
  const int ho = ho0 + mw;
  const int obase = ((n * 28 + ho) * 28) * 256;
  const int ctbase = nh * 8 + nw * 4;

#define LDA(row, colp, sub)                                                              \
  (*(const vi4*)(lds + ((row) * 58 + (colp)) * 32 +                                      \
                 ((sub) ^ ((((row) * 58 + (colp)) & 7) << 2))))

  vi4 acc[2][4];
  vi4 bA[4], bB[4];
  vi4 a0A, a1A, a0B, a1B;

  // ---- identity branch first (2 K-steps) ----
#pragma unroll
  for (int mt = 0; mt < 2; ++mt)
#pragma unroll
    for (int ct = 0; ct < 4; ++ct) acc[mt][ct] = zero;
  const vi4* wibase = Widm + ctbase * 64 + lane;
  {
    const int row = 2 * mw + 1;
#pragma unroll
    for (int kc = 0; kc < 2; ++kc) {
      vi4 a0 = LDA(row, 2 * woc0 + 1, kc * 16 + choff);
      vi4 a1 = LDA(row, 2 * woc1 + 1, kc * 16 + choff);
#pragma unroll
      for (int ct = 0; ct < 4; ++ct) {
        vi4 b = wibase[kc * 1024 + ct * 64];
        acc[0][ct] = MFMA_I8(a0, b, acc[0][ct]);
        acc[1][ct] = MFMA_I8(a1, b, acc[1][ct]);
      }
    }
  }
  int am = 0;
#pragma unroll
  for (int ct = 0; ct < 4; ++ct) {
    const int co = (ctbase + ct) * 16 + lm;
#pragma unroll
    for (int mt = 0; mt < 2; ++mt)
#pragma unroll
      for (int r = 0; r < 4; ++r) {
        int wo = mt * 16 + quad * 4 + r;
        if (wo < 28) {
          int v = acc[mt][ct][r];
          IDI[obase + wo * 256 + co] = v;  // plain store: consumed by k_tail after boundary
          am = max(am, v < 0 ? -v : v);
        }
      }
  }
#pragma unroll
  for (int k = 32; k >= 1; k >>= 1) am = max(am, __shfl_xor(am, k));
  if (lane == 0) redA[wv] = am;

  // ---- main 3x3 conv, 18 K-steps, ping-pong ----
#pragma unroll
  for (int mt = 0; mt < 2; ++mt)
#pragma unroll
    for (int ct = 0; ct < 4; ++ct) acc[mt][ct] = zero;
  const vi4* wbase = W1m + ctbase * 64 + lane;
#pragma unroll
  for (int ct = 0; ct < 4; ++ct) bA[ct] = wbase[ct * 64];
  {
    a0A = LDA(2 * mw, 2 * woc0, choff);
    a1A = LDA(2 * mw, 2 * woc1, choff);
  }
#pragma unroll 1
  for (int ks = 0; ks < 18; ks += 2) {
    {
      const int ksn = ks + 1;
      const int khn = (ksn >= 6) + (ksn >= 12);
      const int t2 = ksn - khn * 6;
      const int kwn = t2 >> 1, kcn = t2 & 1;
#pragma unroll
      for (int ct = 0; ct < 4; ++ct) bB[ct] = wbase[ksn * 1024 + ct * 64];
      const int row = 2 * mw + khn;
      a0B = LDA(row, 2 * woc0 + kwn, kcn * 16 + choff);
      a1B = LDA(row, 2 * woc1 + kwn, kcn * 16 + choff);
    }
#pragma unroll
    for (int ct = 0; ct < 4; ++ct) {
      acc[0][ct] = MFMA_I8(a0A, bA[ct], acc[0][ct]);
      acc[1][ct] = MFMA_I8(a1A, bA[ct], acc[1][ct]);
    }
    if (ks + 2 < 18) {
      const int ksn = ks + 2;
      const int khn = (ksn >= 6) + (ksn >= 12);
      const int t2 = ksn - khn * 6;
      const int kwn = t2 >> 1, kcn = t2 & 1;
#pragma unroll
      for (int ct = 0; ct < 4; ++ct) bA[ct] = wbase[ksn * 1024 + ct * 64];
      const int row = 2 * mw + khn;
      a0A = LDA(row, 2 * woc0 + kwn, kcn * 16 + choff);
      a1A = LDA(row, 2 * woc1 + kwn, kcn * 16 + choff);
    }
#pragma unroll
    for (int ct = 0; ct < 4; ++ct) {
      acc[0][ct] = MFMA_I8(a0B, bB[ct], acc[0][ct]);
      acc[1][ct] = MFMA_I8(a1B, bB[ct], acc[1][ct]);
    }
  }

  // ---- per-channel extrema in REGISTERS + block absmax(h1) ----
  int vmx[4], vmn[4];
  int am1 = 0;
#pragma unroll
  for (int ct = 0; ct < 4; ++ct) {
    int vmax = INT_MIN, vmin = INT_MAX;
#pragma unroll
    for (int mt = 0; mt < 2; ++mt)
#pragma unroll
      for (int r = 0; r < 4; ++r) {
        int wo = mt * 16 + quad * 4 + r;
        if (wo < 28) {
          int v = acc[mt][ct][r];
          vmax = max(vmax, v);
          vmin = min(vmin, v);
        }
      }
    vmax = max(vmax, __shfl_xor(vmax, 16));
    vmax = max(vmax, __shfl_xor(vmax, 32));
    vmin = min(vmin, __shfl_xor(vmin, 16));
    vmin = min(vmin, __shfl_xor(vmin, 32));
    vmx[ct] = vmax;
    vmn[ct] = vmin;
    am1 = max(am1, max(vmax < 0 ? -vmax : vmax, vmin < 0 ? -vmin : vmin));
  }
#pragma unroll
  for (int k = 8; k >= 1; k >>= 1) am1 = max(am1, __shfl_xor(am1, k));
  if (lane == 0) redB[wv] = am1;

  __syncthreads();  // staging reads done -> park may overwrite; redA/redB ready
  // ---- park h1 into LDS [sp=mw*28+wo][130] ----
#pragma unroll
  for (int ct = 0; ct < 4; ++ct) {
    const int cl = (nw * 4 + ct) * 16 + lm;
#pragma unroll
    for (int mt = 0; mt < 2; ++mt)
#pragma unroll
      for (int r = 0; r < 4; ++r) {
        int wo = mt * 16 + quad * 4 + r;
        if (wo < 28) lds[(mw * 28 + wo) * 130 + cl] = acc[mt][ct][r];
      }
  }
  if (tid == 0) {
    atomicMax(IS + 5, max(max(redA[0], redA[1]), max(redA[2], redA[3])));
    atomicMax(IS + 4, max(max(redB[0], redB[1]), max(redB[2], redB[3])));
    gbar(IS, 288, bx, 112);  // B1: mh1 + id amax global
    float sx = sc_slot(IS, 0);
    float sw1 = sc_slot(IS, 1);
    int mh1 = __hip_atomic_load(IS + 4, __ATOMIC_RELAXED, __HIP_MEMORY_SCOPE_AGENT);
    sSxw = sx * sw1;
    sSh1 = fmaxf(sSxw * (float)mh1 / 127.0f, 1e-8f);
  }
  __syncthreads();

  // ---- local rf eval at own per-channel extrema (monotone => exact) ----
  {
    const float sxw = sSxw, s_h1 = sSh1;
    float ym = 0.0f;
#pragma unroll
    for (int ct = 0; ct < 4; ++ct) {
      const int co = (ctbase + ct) * 16 + lm;
      float wq = wq1[co], bbc = b1[co];
      float q1 = clamp8f(rintf((float)vmx[ct] * sxw / s_h1));
      float q0 = clamp8f(rintf((float)vmn[ct] * sxw / s_h1));
      float y1 = fmaxf(q1 * s_h1 * wq + bbc, 0.0f);
      float y0 = fmaxf(q0 * s_h1 * wq + bbc, 0.0f);
      ym = fmaxf(ym, fmaxf(y1, y0));
    }
#pragma unroll
    for (int k = 8; k >= 1; k >>= 1) ym = fmaxf(ym, __shfl_xor(ym, k));
    if (lane == 0) redF[wv] = ym;
  }
  __syncthreads();
  if (tid == 0) {
    atomicMax(IS + 7, __float_as_int(fmaxf(fmaxf(redF[0], redF[1]), fmaxf(redF[2], redF[3]))));
    gbar(IS, 448, bx, 112);  // B2: rf global (short gap after B1 -> tiny skew)
    int mrf = __hip_atomic_load(IS + 7, __ATOMIC_RELAXED, __HIP_MEMORY_SCOPE_AGENT);
    float s_y2 = fmaxf(__int_as_float(mrf) / 127.0f, 1e-8f);
    sSy2 = s_y2;
    if (bx == 0) {
      int mid = __hip_atomic_load(IS + 5, __ATOMIC_RELAXED, __HIP_MEMORY_SCOPE_AGENT);
      float sx = sc_slot(IS, 0);
      float swid = sc_slot(IS, 3);
      SC[9] = s_y2;  // plain stores: kernel-end flush -> visible to k_tail
      SC[10] = fmaxf(sx * swid * (float)mid / 127.0f, 1e-8f);
    }
  }
  __syncthreads();

  // ---- qh1 from parked LDS -> A2 int8 (NHWC, own channel-half), coalesced int writes ----
  {
    const float sxw = sSxw, s_h1 = sSh1, s_y2 = sSy2;
#pragma unroll
    for (int k = 0; k < 7; ++k) {
      int i = tid + k * 256;  // < 1792
      int sp = i >> 5, c4i = i & 31;
      int mwp = sp >= 28 ? 1 : 0;
      int wo = sp - mwp * 28;
      int c0 = nh * 128 + c4i * 4;
      const int* pk = lds + sp * 130 + c4i * 4;
      unsigned r0 = (unsigned char)qact(pk[0], sxw, s_h1, s_y2, wq1[c0], b1[c0]);
      unsigned r1 = (unsigned char)qact(pk[1], sxw, s_h1, s_y2, wq1[c0 + 1], b1[c0 + 1]);
      unsigned r2 = (unsigned char)qact(pk[2], sxw, s_h1, s_y2, wq1[c0 + 2], b1[c0 + 2]);
      unsigned r3 = (unsigned char)qact(pk[3], sxw, s_h1, s_y2, wq1[c0 + 3], b1[c0 + 3]);
      A2i[((n * 28 + ho0 + mwp) * 28 + wo) * 64 + nh * 32 + c4i] =
          (int)(r0 | (r1 << 8) | (r2 << 16) | (r3 << 24));
    }
  }
#undef LDA
}

// ---- residual sum math ----
struct SumParams {
  float sxw2, s_h2, sxwid, s_idq;
};
__device__ __forceinline__ float sum_val(int v2, int vi, const SumParams& P, float wq2c, float b2c,
                                         float wqidc, float bidc) {
  float q2 = clamp8f(rintf((float)v2 * P.sxw2 / P.s_h2));
  float z = (q2 * P.s_h2) * wq2c + b2c;
  float qi = clamp8f(rintf((float)vi * P.sxwid / P.s_idq));
  float zi = (qi * P.s_idq) * wqidc + bidc;
  return z + zi;
}
__device__ __forceinline__ SumParams make_params2(const float* SC, const unsigned* ISu, int mh2) {
  SumParams P;
  float sx = sc_from_bits(ISu[0]);
  float sw2 = sc_from_bits(ISu[2]);
  float swid = sc_from_bits(ISu[3]);
  float s_y2 = SC[9];
  P.s_idq = SC[10];
  P.sxw2 = s_y2 * sw2;
  P.s_h2 = fmaxf(P.sxw2 * (float)mh2 / 127.0f, 1e-8f);
  P.sxwid = sx * swid;
  return P;
}

// Fused tail (r3-proven, ~67us): conv2 3x3 s1 p1 (Cin=256) + residual absmax + requant + NCHW out.
// Fence-free grid barriers at bases 608/768. H2 never hits HBM.
__global__ __launch_bounds__(THREADS, 4) void k_tail(const int* __restrict__ A2,
                                                     const vi4* __restrict__ W2m,
                                                     const int* __restrict__ IDI,
                                                     const float* SC, int* IS,
                                                     const float* __restrict__ wq2,
                                                     const float* __restrict__ b2,
                                                     const float* __restrict__ wqid,
                                                     const float* __restrict__ bidp,
                                                     float* __restrict__ out) {
  __shared__ __align__(16) int lds[4 * 30 * 68];  // 32640B; reused for sums [128][57] f32
  __shared__ int redA[4];
  __shared__ float redF[4];
  __shared__ int sMh2;
  __shared__ float sOutS;
  const int tid = threadIdx.x;
  const int bx = blockIdx.x;
  const int n = bx / 28, rr = bx % 28;
  const int hp = rr >> 1, nh = rr & 1;
  const int ho0 = hp * 2;
  vi4 zero = {0, 0, 0, 0};

  for (int r = 0; r < 4; ++r) {
    int h = ho0 - 1 + r;
    int* dst = lds + r * 30 * 68;
    if (h >= 0 && h < 28) {
      const vi4* src = (const vi4*)(A2 + (n * 28 + h) * 28 * 64);
      for (int i4 = tid; i4 < 448; i4 += THREADS) {
        int col = i4 >> 4, c = (i4 & 15) * 4;
        *(vi4*)(dst + (col + 1) * 68 + c) = src[i4];
      }
      if (tid < 64) dst[tid] = 0;
      else if (tid >= 128 && tid < 192) dst[29 * 68 + (tid - 128)] = 0;
    } else {
      for (int i4 = tid; i4 < 510; i4 += THREADS) ((vi4*)dst)[i4] = zero;
    }
  }
  __syncthreads();

  const int lane = tid & 63, wv = tid >> 6;
  const int mw = wv & 1, nw = wv >> 1;
  const int lm = lane & 15, quad = lane >> 4;
  const int woc0 = lm, woc1 = (16 + lm) > 27 ? 27 : (16 + lm);
  const int choff = quad * 4;
  const int ctbase = nh * 8 + nw * 4;

  vi4 acc[2][4];
  vi4 bA[4], bB[4];
  vi4 a0A, a1A, a0B, a1B;
#pragma unroll
  for (int mt = 0; mt < 2; ++mt)
#pragma unroll
    for (int ct = 0; ct < 4; ++ct) acc[mt][ct] = zero;

  const vi4* wbase = W2m + ctbase * 64 + lane;
#pragma unroll
  for (int ct = 0; ct < 4; ++ct) bA[ct] = wbase[ct * 64];
  {
    const int ro = mw * 30;  // ks=0
    a0A = *(const vi4*)(lds + (ro + woc0) * 68 + choff);
    a1A = *(const vi4*)(lds + (ro + woc1) * 68 + choff);
  }
#pragma unroll 1
  for (int ks = 0; ks < 36; ks += 2) {
    {
      const int ksn = ks + 1;
      const int khn = (ksn >= 12) + (ksn >= 24);
      const int t2 = ksn - khn * 12;
      const int kwn = t2 >> 2, kcn = t2 & 3;
#pragma unroll
      for (int ct = 0; ct < 4; ++ct) bB[ct] = wbase[ksn * 1024 + ct * 64];
      const int ro = (mw + khn) * 30;
      a0B = *(const vi4*)(lds + (ro + woc0 + kwn) * 68 + kcn * 16 + choff);
      a1B = *(const vi4*)(lds + (ro + woc1 + kwn) * 68 + kcn * 16 + choff);
    }
#pragma unroll
    for (int ct = 0; ct < 4; ++ct) {
      acc[0][ct] = MFMA_I8(a0A, bA[ct], acc[0][ct]);
      acc[1][ct] = MFMA_I8(a1A, bA[ct], acc[1][ct]);
    }
    if (ks + 2 < 36) {
      const int ksn = ks + 2;
      const int khn = (ksn >= 12) + (ksn >= 24);
      const int t2 = ksn - khn * 12;
      const int kwn = t2 >> 2, kcn = t2 & 3;
#pragma unroll
      for (int ct = 0; ct < 4; ++ct) bA[ct] = wbase[ksn * 1024 + ct * 64];
      const int ro = (mw + khn) * 30;
      a0A = *(const vi4*)(lds + (ro + woc0 + kwn) * 68 + kcn * 16 + choff);
      a1A = *(const vi4*)(lds + (ro + woc1 + kwn) * 68 + kcn * 16 + choff);
    }
#pragma unroll
    for (int ct = 0; ct < 4; ++ct) {
      acc[0][ct] = MFMA_I8(a0B, bB[ct], acc[0][ct]);
      acc[1][ct] = MFMA_I8(a1B, bB[ct], acc[1][ct]);
    }
  }

  // ---- block max|h2| straight from acc (H2 never stored) ----
  int am = 0;
#pragma unroll
  for (int ct = 0; ct < 4; ++ct)
#pragma unroll
    for (int mt = 0; mt < 2; ++mt)
#pragma unroll
      for (int r = 0; r < 4; ++r) {
        int wo = mt * 16 + quad * 4 + r;
        if (wo < 28) {
          int v = acc[mt][ct][r];
          am = max(am, v < 0 ? -v : v);
        }
      }
#pragma unroll
  for (int k = 32; k >= 1; k >>= 1) am = max(am, __shfl_xor(am, k));
  if (lane == 0) redA[wv] = am;
  __syncthreads();
  if (tid == 0) {
    int a = max(max(redA[0], redA[1]), max(redA[2], redA[3]));
    atomicMax(IS + 6, a);  // device RMW (coherence point)
  }

  // ---- stage this block's IDI half into LDS, transposed [cl][sp] (pad 57) ----
  int* sumsi = lds;
  float* sums = (float*)lds;
  const int ib = ((n * 28 + ho0) * 28) * 256 + nh * 128;
#pragma unroll
  for (int k = 0; k < 28; ++k) {
    int idx = tid + k * 256;            // 0..7167
    int cl = idx & 127, sp = idx >> 7;  // sp = hl*28+wo
    sumsi[cl * 57 + sp] = IDI[ib + sp * 256 + cl];
  }
  __syncthreads();
  if (tid == 0) {
    gbar(IS, 608, bx, 112);  // B: max|h2| global
    sMh2 = __hip_atomic_load(IS + 6, __ATOMIC_RELAXED, __HIP_MEMORY_SCOPE_SYSTEM);
  }
  __syncthreads();
  const SumParams P = make_params2(SC, (const unsigned*)IS, sMh2);

  // ---- RMW owned slots: sum = z + zi; track |sum| ----
  float fm = 0.0f;
#pragma unroll
  for (int ct = 0; ct < 4; ++ct) {
    const int co = (ctbase + ct) * 16 + lm;
    const int cl = co - nh * 128;
    float w2c = wq2[co], b2c = b2[co], wic = wqid[co], bic = bidp[co];
#pragma unroll
    for (int mt = 0; mt < 2; ++mt)
#pragma unroll
      for (int r = 0; r < 4; ++r) {
        int wo = mt * 16 + quad * 4 + r;
        if (wo < 28) {
          int slot = cl * 57 + mw * 28 + wo;
          float sv = sum_val(acc[mt][ct][r], sumsi[slot], P, w2c, b2c, wic, bic);
          sums[slot] = sv;
          fm = fmaxf(fm, fabsf(sv));
        }
      }
  }
#pragma unroll
  for (int k = 32; k >= 1; k >>= 1) fm = fmaxf(fm, __shfl_xor(fm, k));
  if (lane == 0) redF[wv] = fm;
  __syncthreads();
  if (tid == 0) {
    float a = fmaxf(fmaxf(redF[0], redF[1]), fmaxf(redF[2], redF[3]));
    atomicMax(IS + 11, __float_as_int(a));
    gbar(IS, 768, bx, 112);  // B: max|sum| global
    int mb = __hip_atomic_load(IS + 11, __ATOMIC_RELAXED, __HIP_MEMORY_SCOPE_SYSTEM);
    sOutS = fmaxf(__int_as_float(mb) / 127.0f, 1e-8f);
  }
  __syncthreads();
  const float out_s = sOutS;

  // ---- requant + relu, NCHW write ----
  float* ob = out + n * 200704 + (nh * 128) * 784 + ho0 * 28;
#pragma unroll
  for (int k = 0; k < 28; ++k) {
    int idx = tid + k * 256;
    int cl = idx / 56, rem = idx % 56;
    float sv = sums[cl * 57 + rem];
    float q = clamp8f(rintf(sv / out_s));
    ob[cl * 784 + rem] = q > 0.0f ? q * out_s : 0.0f;
  }
  if (bx == 0 && tid == 0) out[6422528] = out_s;
}

extern "C" void kernel_launch(void* const* d_in, const int* in_sizes, int n_in, void* d_out,
                              int out_size, void* d_ws, size_t ws_size, hipStream_t stream) {
  (void)in_sizes; (void)n_in; (void)out_size; (void)ws_size;
  const float* x = (const float*)d_in[0];
  const float* w1 = (const float*)d_in[1];
  const float* w2 = (const float*)d_in[2];
  const float* wid = (const float*)d_in[3];
  const float* bn1g = (const float*)d_in[4];
  const float* bn1b = (const float*)d_in[5];
  const float* bn1m = (const float*)d_in[6];
  const float* bn1v = (const float*)d_in[7];
  const float* bn2g = (const float*)d_in[8];
  const float* bn2b = (const float*)d_in[9];
  const float* bn2m = (const float*)d_in[10];
  const float* bn2v = (const float*)d_in[11];
  const float* idg = (const float*)d_in[12];
  const float* idb = (const float*)d_in[13];
  const float* idm = (const float*)d_in[14];
  const float* idv = (const float*)d_in[15];

  char* ws = (char*)d_ws;
  float* SC = (float*)ws;
  int* IS = (int*)ws;
  unsigned* ISu = (unsigned*)ws;
  // barrier counters occupy IS[128..1024); per-channel tables after:
  float* wq1 = (float*)(ws + 4096);
  float* b1 = (float*)(ws + 5120);
  float* wq2 = (float*)(ws + 6144);
  float* b2 = (float*)(ws + 7168);
  float* wqid = (float*)(ws + 8192);
  float* bid = (float*)(ws + 9216);
  char* X8 = ws + 16384;  // NHWC int8; A2 overlays (all X8 reads complete before qh1 writes)
  char* A2 = X8;
  char* W1m = X8 + 12845056;
  char* W2m = W1m + 294912;
  char* Widm = W2m + 589824;
  int* IDI = (int*)(Widm + 32768);
  float* out = (float*)d_out;

  k_pre<<<723, THREADS, 0, stream>>>(IS, bn1g, bn1b, bn1m, bn1v, wq1, b1, bn2g, bn2b, bn2m, bn2v,
                                     wq2, b2, idg, idb, idm, idv, wqid, bid, (const float4*)w1,
                                     (const float4*)w2, (const float4*)wid, (const float4*)x);
  k_quant<<<2016, THREADS, 0, stream>>>(x, (int*)X8, w1, (vi4*)W1m, w2, (vi4*)W2m, wid,
                                        (vi4*)Widm, ISu);
  k_cv1<<<GRID_BLOCKS, THREADS, 0, stream>>>((const int*)X8, (const vi4*)W1m, (const vi4*)Widm,
                                             IDI, (int*)A2, IS, wq1, b1, SC);
  k_tail<<<GRID_BLOCKS, THREADS, 0, stream>>>((const int*)A2, (const vi4*)W2m, (const int*)IDI, SC,
                                              IS, wq2, b2, wqid, bid, out);
}

// Round 11
// 249.843 us; speedup vs baseline: 1.2589x; 1.0382x over previous
//
#include <hip/hip_runtime.h>
#include <limits.h>

#define THREADS 256
#define GRID_BLOCKS 896

typedef int vi4 __attribute__((ext_vector_type(4)));

__device__ __forceinline__ float clamp8f(float q) { return fminf(fmaxf(q, -128.0f), 127.0f); }
__device__ __forceinline__ float sc_from_bits(unsigned b) {
  return fmaxf(__uint_as_float(b) / 127.0f, 1e-8f);
}
__device__ __forceinline__ signed char q8(float v, float s) {
  return (signed char)(int)clamp8f(rintf(v / s));
}

// ===== r11: re-run of the r4 configuration (best measured: 246.9us). r10's core dump was a
// process abort with no accuracy signal on a freshly-acquired node; single prior clean pass
// (r4, incl. rocprof replays) + full structural re-audit -> treat as transient, re-measure.
// Session ledger:
//  r1: hipLaunchCooperativeKernel not graph-capturable -> silent no-op. Use sw barrier.
//  r2: acquire-per-poll spin = L2 cache-maintenance storm (310us k_tail). Fence-free only.
//  r3: fence-free hierarchical barrier works: k_tail 67us, H2 never hits HBM.
//  r4: cv1 fused (conv1+scales+qh1, 3 barriers + d_out extrema scratch) -> 246.9us BEST.
//  r5: 2016-block barrier front needs (256,8)->64 VGPR, kills load pipelining (+26us).
//  r6-r9: qx-float4 exonerated (r8); hipMemsetAsync exonerated (r9); cv1-r5 rewrite is the
//         ~12us regression (259-262us family) despite less nominal work -> keep cv1-r4.
//  r7: register-parked x spills at (256,4); k_tail dur modulated by front-induced start skew.
//  r10: r4-restore core-dumped (node flake suspected); this round decides.
// Scalar slots: [0] amax_x [1] amax_w1 [2] amax_w2 [3] amax_wid
// [4] maxabs_h1 [5] maxabs_id [6] maxabs_h2 [7] max_y2(rf bits) [9] s_y2 [10] s_idq [11] amax_sum
// Grid barriers (zeroed by k_pre b==0): bases k_cv1 128,288,448; k_tail 608,768.
// Per base B: subs B+s*16 (s<8, 112 blocks each), root B+128, flag B+144. Max idx 912.
// All value slots use SIGNED atomicMax; harness 0xAA poison is negative as int -> no init pass.

__device__ __forceinline__ void gbar(int* IS, int base, int bx) {
  // fence-free barrier (r3-proven): relaxed hierarchical arrive + relaxed system poll.
  // Caller: __syncthreads() before (drains all waves' vmem incl. agent stores) and after.
  asm volatile("s_waitcnt vmcnt(0)" ::: "memory");  // tid0's own RMWs complete before arrive
  int old = __hip_atomic_fetch_add(IS + base + (bx & 7) * 16, 1, __ATOMIC_RELAXED,
                                   __HIP_MEMORY_SCOPE_AGENT);
  if (old == 111) {
    int r = __hip_atomic_fetch_add(IS + base + 128, 1, __ATOMIC_RELAXED, __HIP_MEMORY_SCOPE_AGENT);
    if (r == 7)
      __hip_atomic_fetch_add(IS + base + 144, 1, __ATOMIC_RELAXED, __HIP_MEMORY_SCOPE_AGENT);
  }
  while (__hip_atomic_load(IS + base + 144, __ATOMIC_RELAXED, __HIP_MEMORY_SCOPE_SYSTEM) == 0)
    __builtin_amdgcn_s_sleep(2);
}

__device__ __forceinline__ void amax_body(const float4* __restrict__ p, int n4, int bid,
                                          int nblocks, int* __restrict__ slot) {
  const int tid = threadIdx.x;
  const int stride = nblocks * THREADS;
  float m = 0.0f;
  int i = bid * THREADS + tid;
  for (; i + 3 * stride < n4; i += 4 * stride) {
    float4 v0 = p[i];
    float4 v1 = p[i + stride];
    float4 v2 = p[i + 2 * stride];
    float4 v3 = p[i + 3 * stride];
    float m0 = fmaxf(fmaxf(fabsf(v0.x), fabsf(v0.y)), fmaxf(fabsf(v0.z), fabsf(v0.w)));
    float m1 = fmaxf(fmaxf(fabsf(v1.x), fabsf(v1.y)), fmaxf(fabsf(v1.z), fabsf(v1.w)));
    float m2 = fmaxf(fmaxf(fabsf(v2.x), fabsf(v2.y)), fmaxf(fabsf(v2.z), fabsf(v2.w)));
    float m3 = fmaxf(fmaxf(fabsf(v3.x), fabsf(v3.y)), fmaxf(fabsf(v3.z), fabsf(v3.w)));
    m = fmaxf(m, fmaxf(fmaxf(m0, m1), fmaxf(m2, m3)));
  }
  for (; i < n4; i += stride) {
    float4 v = p[i];
    m = fmaxf(m, fmaxf(fmaxf(fabsf(v.x), fabsf(v.y)), fmaxf(fabsf(v.z), fabsf(v.w))));
  }
#pragma unroll
  for (int k = 32; k >= 1; k >>= 1) m = fmaxf(m, __shfl_xor(m, k));
  __shared__ float wred[4];
  if ((tid & 63) == 0) wred[tid >> 6] = m;
  __syncthreads();
  if (tid == 0) {
    m = fmaxf(fmaxf(wred[0], wred[1]), fmaxf(wred[2], wred[3]));
    atomicMax(slot, __float_as_int(m));
  }
}

// Merged: blocks 0-2 bnfold(bn1,bn2,id); 3..66 w1 amax; 67..194 w2; 195..210 wid; 211..722 x.
// Block 0 also zeroes all grid-barrier counters (IS[128..928)) for this launch/replay.
__global__ __launch_bounds__(THREADS) void k_pre(
    int* IS, const float* g1, const float* be1, const float* m1, const float* v1, float* wq1,
    float* b1, const float* g2, const float* be2, const float* m2, const float* v2, float* wq2,
    float* b2, const float* gi, const float* bei, const float* mi, const float* vvi, float* wqi,
    float* bi, const float4* w1, const float4* w2, const float4* wid, const float4* x) {
  int b = blockIdx.x;
  int c = threadIdx.x;
  if (b < 3) {
    if (b == 0) {
      IS[128 + c] = 0;
      IS[384 + c] = 0;
      IS[640 + c] = 0;
      if (c < 32) IS[896 + c] = 0;
    }
    const float *gamma, *beta, *mean, *var;
    float *wq, *bb;
    if (b == 0) { gamma = g1; beta = be1; mean = m1; var = v1; wq = wq1; bb = b1; }
    else if (b == 1) { gamma = g2; beta = be2; mean = m2; var = v2; wq = wq2; bb = b2; }
    else { gamma = gi; beta = bei; mean = mi; var = vvi; wq = wqi; bb = bi; }
    __shared__ float red[THREADS];
    float ws = gamma[c] * (1.0f / sqrtf(var[c] + 1e-5f));
    red[c] = fabsf(ws);
    __syncthreads();
    for (int s = THREADS / 2; s > 0; s >>= 1) {
      if (c < s) red[c] = fmaxf(red[c], red[c + s]);
      __syncthreads();
    }
    float sws = fmaxf(red[0] / 127.0f, 1e-8f);
    float q = clamp8f(rintf(ws / sws)) * sws;
    wq[c] = q;
    bb[c] = beta[c] - mean[c] * q;
    return;
  }
  b -= 3;
  if (b < 64) { amax_body(w1, 73728, b, 64, IS + 1); return; }
  b -= 64;
  if (b < 128) { amax_body(w2, 147456, b, 128, IS + 2); return; }
  b -= 128;
  if (b < 16) { amax_body(wid, 8192, b, 16, IS + 3); return; }
  b -= 16;
  amax_body(x, 3211264, b, 512, IS + 0);
}

// Merged quantize: blocks [0,1792) qx; [1792,1864) qw1; [1864,2008) qw2; [2008,2016) qwid.
__global__ __launch_bounds__(THREADS) void k_quant(const float* __restrict__ x,
                                                   int* __restrict__ X8,
                                                   const float* __restrict__ w1f,
                                                   vi4* __restrict__ W1m,
                                                   const float* __restrict__ w2f,
                                                   vi4* __restrict__ W2m,
                                                   const float* __restrict__ widf,
                                                   vi4* __restrict__ Widm,
                                                   const unsigned* __restrict__ ISu) {
  __shared__ signed char tile[56 * 132];
  int b = blockIdx.x;
  int t = threadIdx.x;
  if (b < 1792) {
    float s = sc_from_bits(ISu[0]);
    int h = b % 56, n = b / 56;
    const float* xp = x + ((n * 128) * 56 + h) * 56;
#pragma unroll
    for (int k = 0; k < 28; ++k) {
      int i = t + k * 256;  // < 7168
      int w = i % 56, c = i / 56;
      tile[w * 132 + c] = q8(xp[c * 3136 + w], s);
    }
    __syncthreads();
    int* op = X8 + (n * 56 + h) * 56 * 32;
#pragma unroll
    for (int k = 0; k < 7; ++k) {
      int i = t + k * 256;  // < 1792
      int w = i >> 5, c4 = (i & 31) * 4;
      const signed char* tp = tile + w * 132 + c4;
      op[i] = (int)(unsigned char)tp[0] | ((int)(unsigned char)tp[1] << 8) |
              ((int)(unsigned char)tp[2] << 16) | ((int)(unsigned char)tp[3] << 24);
    }
    return;
  }
  if (b < 1864) {
    int tt = (b - 1792) * THREADS + t;  // < 18432
    float s = sc_from_bits(ISu[1]);
    int lane = tt & 63;
    int cotile = (tt >> 6) & 15;
    int ks = tt >> 10;  // 0..17
    int tap = ks >> 1, kc = ks & 1;
    int kh = tap / 3, kw = tap % 3;
    int co = cotile * 16 + (lane & 15);
    int ci0 = kc * 64 + (lane >> 4) * 16;
    const float* src = w1f + (co * 128 + ci0) * 9 + kh * 3 + kw;
    int r[4];
#pragma unroll
    for (int q = 0; q < 4; ++q) {
      unsigned b0 = (unsigned char)q8(src[(q * 4 + 0) * 9], s);
      unsigned b1 = (unsigned char)q8(src[(q * 4 + 1) * 9], s);
      unsigned b2 = (unsigned char)q8(src[(q * 4 + 2) * 9], s);
      unsigned b3 = (unsigned char)q8(src[(q * 4 + 3) * 9], s);
      r[q] = (int)(b0 | (b1 << 8) | (b2 << 16) | (b3 << 24));
    }
    vi4 v = {r[0], r[1], r[2], r[3]};
    W1m[tt] = v;
    return;
  }
  if (b < 2008) {
    int tt = (b - 1864) * THREADS + t;  // < 36864
    float s = sc_from_bits(ISu[2]);
    int lane = tt & 63;
    int cotile = (tt >> 6) & 15;
    int ks = tt >> 10;  // 0..35
    int tap = ks >> 2, kc = ks & 3;
    int kh = tap / 3, kw = tap % 3;
    int co = cotile * 16 + (lane & 15);
    int ci0 = kc * 64 + (lane >> 4) * 16;
    const float* src = w2f + (co * 256 + ci0) * 9 + kh * 3 + kw;
    int r[4];
#pragma unroll
    for (int q = 0; q < 4; ++q) {
      unsigned b0 = (unsigned char)q8(src[(q * 4 + 0) * 9], s);
      unsigned b1 = (unsigned char)q8(src[(q * 4 + 1) * 9], s);
      unsigned b2 = (unsigned char)q8(src[(q * 4 + 2) * 9], s);
      unsigned b3 = (unsigned char)q8(src[(q * 4 + 3) * 9], s);
      r[q] = (int)(b0 | (b1 << 8) | (b2 << 16) | (b3 << 24));
    }
    vi4 v = {r[0], r[1], r[2], r[3]};
    W2m[tt] = v;
    return;
  }
  {
    int tt = (b - 2008) * THREADS + t;  // < 2048
    float s = sc_from_bits(ISu[3]);
    int lane = tt & 63;
    int cotile = (tt >> 6) & 15;
    int ks = tt >> 10;  // 0..1
    int co = cotile * 16 + (lane & 15);
    int ci0 = ks * 64 + (lane >> 4) * 16;
    const float* src = widf + co * 128 + ci0;
    int r[4];
#pragma unroll
    for (int q = 0; q < 4; ++q) {
      unsigned b0 = (unsigned char)q8(src[q * 4 + 0], s);
      unsigned b1 = (unsigned char)q8(src[q * 4 + 1], s);
      unsigned b2 = (unsigned char)q8(src[q * 4 + 2], s);
      unsigned b3 = (unsigned char)q8(src[q * 4 + 3], s);
      r[q] = (int)(b0 | (b1 << 8) | (b2 << 16) | (b3 << 24));
    }
    vi4 v = {r[0], r[1], r[2], r[3]};
    Widm[tt] = v;
  }
}

#define MFMA_I8(a, b, c) __builtin_amdgcn_mfma_i32_16x16x64_i8(a, b, c, 0, 0, 0)

// quant(h1) -> bn1 -> relu -> quant (scalar form, used in k_cv1 qh1 phase)
__device__ __forceinline__ signed char qact(int v, float sxw, float s_h1, float s_y2, float wq,
                                            float bb) {
  float hf = (float)v * sxw;
  float q = clamp8f(rintf(hf / s_h1));
  float hv = q * s_h1;
  float y = fmaxf(hv * wq + bb, 0.0f);
  float a = fminf(fmaxf(rintf(y / s_y2), -128.0f), 127.0f);
  return (signed char)(int)a;
}

__device__ __forceinline__ float sc_slot(const int* IS, int slot) {
  unsigned u = (unsigned)__hip_atomic_load((int*)(IS + slot), __ATOMIC_RELAXED,
                                           __HIP_MEMORY_SCOPE_AGENT);
  return fmaxf(__uint_as_float(u) / 127.0f, 1e-8f);
}

// Fused conv1 stage (r4 version — best measured): conv1 3x3 s2 p1 (Cin=128) + identity 1x1 s2 +
// grid-wide scale derivation + qh1 => A2 int8, THREE fence-free barriers, per-channel extrema
// exchanged via AGENT-scope stores to d_out scratch (256-block reduce between B1/B2).
// H1 parked in LDS, never HBM. LDS staging XOR-swizzled stride-32 (37.1KB).
// (256,4): 4 blk/CU x 256 CU = 1024 >= 896 co-resident by construction.
__global__ __launch_bounds__(THREADS, 4) void k_cv1(const int* X8, const vi4* __restrict__ W1m,
                                                    const vi4* __restrict__ Widm,
                                                    int* __restrict__ IDI, int* A2i, int* IS,
                                                    const float* __restrict__ wq1,
                                                    const float* __restrict__ b1, float* SC,
                                                    int* maxS2, int* minS2) {
  __shared__ __align__(16) int lds[9280];  // stage 5*58*32; later park h1 [56][130] + reduce
  __shared__ int redA[4];
  __shared__ int sVmax, sVmin;
  __shared__ float sSxw, sSh1, sSy2;
  const int tid = threadIdx.x;
  const int bx = blockIdx.x;
  const int n = bx / 28, rr = bx % 28;
  const int hp = rr >> 1, nh = rr & 1;
  const int ho0 = hp * 2;
  vi4 zero = {0, 0, 0, 0};

  // ---- stage 5 input rows, swizzled stride-32 ----
  for (int r = 0; r < 5; ++r) {
    int h = 2 * ho0 - 1 + r;
    int* dst = lds + r * 58 * 32;
    if (h >= 0 && h < 56) {
      const vi4* src = (const vi4*)(X8 + (n * 56 + h) * 56 * 32);
      for (int i4 = tid; i4 < 448; i4 += THREADS) {
        int col = i4 >> 3, e0 = (i4 & 7) * 4;
        int cell = r * 58 + col + 1;
        *(vi4*)(lds + cell * 32 + (e0 ^ ((cell & 7) << 2))) = src[i4];
      }
      if (tid < 32) dst[tid] = 0;                                    // left pad cell
      else if (tid >= 128 && tid < 160) dst[57 * 32 + (tid - 128)] = 0;  // right pad cell
    } else {
      for (int i4 = tid; i4 < 464; i4 += THREADS) ((vi4*)dst)[i4] = zero;
    }
  }
  __syncthreads();

  const int lane = tid & 63, wv = tid >> 6;
  const int mw = wv & 1, nw = wv >> 1;
  const int lm = lane & 15, quad = lane >> 4;
  const int woc0 = lm, woc1 = (16 + lm) > 27 ? 27 : (16 + lm);
  const int choff = quad * 4;
  const int ho = ho0 + mw;
  const int obase = ((n * 28 + ho) * 28) * 256;
  const int ctbase = nh * 8 + nw * 4;

#define LDA(row, colp, sub)                                                              \
  (*(const vi4*)(lds + ((row) * 58 + (colp)) * 32 +                                      \
                 ((sub) ^ ((((row) * 58 + (colp)) & 7) << 2))))

  vi4 acc[2][4];
  vi4 bA[4], bB[4];
  vi4 a0A, a1A, a0B, a1B;

  // ---- identity branch first (2 K-steps) ----
#pragma unroll
  for (int mt = 0; mt < 2; ++mt)
#pragma unroll
    for (int ct = 0; ct < 4; ++ct) acc[mt][ct] = zero;
  const vi4* wibase = Widm + ctbase * 64 + lane;
  {
    const int row = 2 * mw + 1;
#pragma unroll
    for (int kc = 0; kc < 2; ++kc) {
      vi4 a0 = LDA(row, 2 * woc0 + 1, kc * 16 + choff);
      vi4 a1 = LDA(row, 2 * woc1 + 1, kc * 16 + choff);
#pragma unroll
      for (int ct = 0; ct < 4; ++ct) {
        vi4 b = wibase[kc * 1024 + ct * 64];
        acc[0][ct] = MFMA_I8(a0, b, acc[0][ct]);
        acc[1][ct] = MFMA_I8(a1, b, acc[1][ct]);
      }
    }
  }
  int am = 0;
#pragma unroll
  for (int ct = 0; ct < 4; ++ct) {
    const int co = (ctbase + ct) * 16 + lm;
#pragma unroll
    for (int mt = 0; mt < 2; ++mt)
#pragma unroll
      for (int r = 0; r < 4; ++r) {
        int wo = mt * 16 + quad * 4 + r;
        if (wo < 28) {
          int v = acc[mt][ct][r];
          IDI[obase + wo * 256 + co] = v;  // plain store: consumed by k_tail after boundary
          am = max(am, v < 0 ? -v : v);
        }
      }
  }
#pragma unroll
  for (int k = 32; k >= 1; k >>= 1) am = max(am, __shfl_xor(am, k));
  if (lane == 0) redA[wv] = am;

  // ---- main 3x3 conv, 18 K-steps, ping-pong ----
#pragma unroll
  for (int mt = 0; mt < 2; ++mt)
#pragma unroll
    for (int ct = 0; ct < 4; ++ct) acc[mt][ct] = zero;
  const vi4* wbase = W1m + ctbase * 64 + lane;
#pragma unroll
  for (int ct = 0; ct < 4; ++ct) bA[ct] = wbase[ct * 64];
  {
    a0A = LDA(2 * mw, 2 * woc0, choff);
    a1A = LDA(2 * mw, 2 * woc1, choff);
  }
#pragma unroll 1
  for (int ks = 0; ks < 18; ks += 2) {
    {
      const int ksn = ks + 1;
      const int khn = (ksn >= 6) + (ksn >= 12);
      const int t2 = ksn - khn * 6;
      const int kwn = t2 >> 1, kcn = t2 & 1;
#pragma unroll
      for (int ct = 0; ct < 4; ++ct) bB[ct] = wbase[ksn * 1024 + ct * 64];
      const int row = 2 * mw + khn;
      a0B = LDA(row, 2 * woc0 + kwn, kcn * 16 + choff);
      a1B = LDA(row, 2 * woc1 + kwn, kcn * 16 + choff);
    }
#pragma unroll
    for (int ct = 0; ct < 4; ++ct) {
      acc[0][ct] = MFMA_I8(a0A, bA[ct], acc[0][ct]);
      acc[1][ct] = MFMA_I8(a1A, bA[ct], acc[1][ct]);
    }
    if (ks + 2 < 18) {
      const int ksn = ks + 2;
      const int khn = (ksn >= 6) + (ksn >= 12);
      const int t2 = ksn - khn * 6;
      const int kwn = t2 >> 1, kcn = t2 & 1;
#pragma unroll
      for (int ct = 0; ct < 4; ++ct) bA[ct] = wbase[ksn * 1024 + ct * 64];
      const int row = 2 * mw + khn;
      a0A = LDA(row, 2 * woc0 + kwn, kcn * 16 + choff);
      a1A = LDA(row, 2 * woc1 + kwn, kcn * 16 + choff);
    }
#pragma unroll
    for (int ct = 0; ct < 4; ++ct) {
      acc[0][ct] = MFMA_I8(a0B, bB[ct], acc[0][ct]);
      acc[1][ct] = MFMA_I8(a1B, bB[ct], acc[1][ct]);
    }
  }

  // ---- per-channel extrema -> d_out scratch via AGENT stores (cross-XCD visible) ----
#pragma unroll
  for (int ct = 0; ct < 4; ++ct) {
    int vmax = INT_MIN, vmin = INT_MAX;
#pragma unroll
    for (int mt = 0; mt < 2; ++mt)
#pragma unroll
      for (int r = 0; r < 4; ++r) {
        int wo = mt * 16 + quad * 4 + r;
        if (wo < 28) {
          int v = acc[mt][ct][r];
          vmax = max(vmax, v);
          vmin = min(vmin, v);
        }
      }
    vmax = max(vmax, __shfl_xor(vmax, 16));
    vmax = max(vmax, __shfl_xor(vmax, 32));
    vmin = min(vmin, __shfl_xor(vmin, 16));
    vmin = min(vmin, __shfl_xor(vmin, 32));
    if (lane < 16) {
      int cl = (nw * 4 + ct) * 16 + lane;
      __hip_atomic_store(maxS2 + bx * 256 + mw * 128 + cl, vmax, __ATOMIC_RELAXED,
                         __HIP_MEMORY_SCOPE_AGENT);
      __hip_atomic_store(minS2 + bx * 256 + mw * 128 + cl, vmin, __ATOMIC_RELAXED,
                         __HIP_MEMORY_SCOPE_AGENT);
    }
  }

  __syncthreads();  // stage reads done grid-block-wide; redA ready; drains all waves' stores
  if (tid == 0) {
    int a = max(max(redA[0], redA[1]), max(redA[2], redA[3]));
    atomicMax(IS + 5, a);  // id amax (device RMW)
  }
  // ---- park h1 into LDS [sp=mw*28+wo][130] (stage dead) ----
#pragma unroll
  for (int ct = 0; ct < 4; ++ct) {
    const int cl = (nw * 4 + ct) * 16 + lm;
#pragma unroll
    for (int mt = 0; mt < 2; ++mt)
#pragma unroll
      for (int r = 0; r < 4; ++r) {
        int wo = mt * 16 + quad * 4 + r;
        if (wo < 28) lds[(mw * 28 + wo) * 130 + cl] = acc[mt][ct][r];
      }
  }
  __syncthreads();  // park + IS[5] RMW visible-block-wide; waves' vmem drained
  if (tid == 0) gbar(IS, 128, bx);  // B1: extrema + IS[5] global
  __syncthreads();

  // ---- rs1a: 256 blocks reduce per-channel extrema over 896 (block,mw) rows ----
  if (bx < 256) {
    const int c = bx, nhc = c >> 7, cl = c & 127;
    int vmax = INT_MIN, vmin = INT_MAX;
    for (int j = tid; j < 896; j += THREADS) {
      int bxx = nhc + ((j >> 1) << 1);
      int mwj = j & 1;
      int a = __hip_atomic_load(maxS2 + bxx * 256 + mwj * 128 + cl, __ATOMIC_RELAXED,
                                __HIP_MEMORY_SCOPE_AGENT);
      int i_ = __hip_atomic_load(minS2 + bxx * 256 + mwj * 128 + cl, __ATOMIC_RELAXED,
                                 __HIP_MEMORY_SCOPE_AGENT);
      vmax = max(vmax, a);
      vmin = min(vmin, i_);
    }
    int* rMax = lds + 7280;
    int* rMin = lds + 7536;
    rMax[tid] = vmax;
    rMin[tid] = vmin;
    __syncthreads();
    for (int s = 128; s > 0; s >>= 1) {
      if (tid < s) {
        rMax[tid] = max(rMax[tid], rMax[tid + s]);
        rMin[tid] = min(rMin[tid], rMin[tid + s]);
      }
      __syncthreads();
    }
    if (tid == 0) {
      sVmax = rMax[0];
      sVmin = rMin[0];
      int a1 = sVmax < 0 ? -sVmax : sVmax;
      int a0 = sVmin < 0 ? -sVmin : sVmin;
      atomicMax(IS + 4, max(a1, a0));  // mh1
    }
  }
  __syncthreads();
  if (tid == 0) gbar(IS, 288, bx);  // B2: mh1 global
  __syncthreads();

  // ---- rs1b: per-channel rf -> IS[7] ----
  if (bx < 256 && tid == 0) {
    float sx = sc_slot(IS, 0);
    float sw1 = sc_slot(IS, 1);
    int mh1 = __hip_atomic_load(IS + 4, __ATOMIC_RELAXED, __HIP_MEMORY_SCOPE_AGENT);
    float sxw = sx * sw1;
    float s_h1 = fmaxf(sxw * (float)mh1 / 127.0f, 1e-8f);
    float wq = wq1[bx], bbc = b1[bx];
    float q1 = clamp8f(rintf((float)sVmax * sxw / s_h1));
    float q0 = clamp8f(rintf((float)sVmin * sxw / s_h1));
    float y1 = fmaxf(q1 * s_h1 * wq + bbc, 0.0f);
    float y0 = fmaxf(q0 * s_h1 * wq + bbc, 0.0f);
    atomicMax(IS + 7, __float_as_int(fmaxf(y1, y0)));  // rf >= 0
  }
  __syncthreads();
  if (tid == 0) gbar(IS, 448, bx);  // B3: rf global
  __syncthreads();

  // ---- scales local; block 0 persists SC[9]/SC[10] for k_tail ----
  if (tid == 0) {
    float sx = sc_slot(IS, 0);
    float sw1 = sc_slot(IS, 1);
    int mh1 = __hip_atomic_load(IS + 4, __ATOMIC_RELAXED, __HIP_MEMORY_SCOPE_AGENT);
    int mrf = __hip_atomic_load(IS + 7, __ATOMIC_RELAXED, __HIP_MEMORY_SCOPE_AGENT);
    float sxw = sx * sw1;
    float s_h1 = fmaxf(sxw * (float)mh1 / 127.0f, 1e-8f);
    float s_y2 = fmaxf(__int_as_float(mrf) / 127.0f, 1e-8f);
    sSxw = sxw;
    sSh1 = s_h1;
    sSy2 = s_y2;
    if (bx == 0) {
      int mid = __hip_atomic_load(IS + 5, __ATOMIC_RELAXED, __HIP_MEMORY_SCOPE_AGENT);
      float swid = sc_slot(IS, 3);
      SC[9] = s_y2;  // plain stores: kernel-end flush -> visible to k_tail
      SC[10] = fmaxf(sx * swid * (float)mid / 127.0f, 1e-8f);
    }
  }
  __syncthreads();

  // ---- qh1 from parked LDS -> A2 int8 (NHWC, own channel-half), coalesced int writes ----
  {
    const float sxw = sSxw, s_h1 = sSh1, s_y2 = sSy2;
#pragma unroll
    for (int k = 0; k < 7; ++k) {
      int i = tid + k * 256;  // < 1792
      int sp = i >> 5, c4i = i & 31;
      int mwp = sp >= 28 ? 1 : 0;
      int wo = sp - mwp * 28;
      int c0 = nh * 128 + c4i * 4;
      const int* pk = lds + sp * 130 + c4i * 4;
      unsigned r0 = (unsigned char)qact(pk[0], sxw, s_h1, s_y2, wq1[c0], b1[c0]);
      unsigned r1 = (unsigned char)qact(pk[1], sxw, s_h1, s_y2, wq1[c0 + 1], b1[c0 + 1]);
      unsigned r2 = (unsigned char)qact(pk[2], sxw, s_h1, s_y2, wq1[c0 + 2], b1[c0 + 2]);
      unsigned r3 = (unsigned char)qact(pk[3], sxw, s_h1, s_y2, wq1[c0 + 3], b1[c0 + 3]);
      A2i[((n * 28 + ho0 + mwp) * 28 + wo) * 64 + nh * 32 + c4i] =
          (int)(r0 | (r1 << 8) | (r2 << 16) | (r3 << 24));
    }
  }
#undef LDA
}

// ---- residual sum math ----
struct SumParams {
  float sxw2, s_h2, sxwid, s_idq;
};
__device__ __forceinline__ float sum_val(int v2, int vi, const SumParams& P, float wq2c, float b2c,
                                         float wqidc, float bidc) {
  float q2 = clamp8f(rintf((float)v2 * P.sxw2 / P.s_h2));
  float z = (q2 * P.s_h2) * wq2c + b2c;
  float qi = clamp8f(rintf((float)vi * P.sxwid / P.s_idq));
  float zi = (qi * P.s_idq) * wqidc + bidc;
  return z + zi;
}
__device__ __forceinline__ SumParams make_params2(const float* SC, const unsigned* ISu, int mh2) {
  SumParams P;
  float sx = sc_from_bits(ISu[0]);
  float sw2 = sc_from_bits(ISu[2]);
  float swid = sc_from_bits(ISu[3]);
  float s_y2 = SC[9];
  P.s_idq = SC[10];
  P.sxw2 = s_y2 * sw2;
  P.s_h2 = fmaxf(P.sxw2 * (float)mh2 / 127.0f, 1e-8f);
  P.sxwid = sx * swid;
  return P;
}

// Fused tail (r3-proven, ~67us): conv2 3x3 s1 p1 (Cin=256) + residual absmax + requant + NCHW out.
// Fence-free grid barriers at bases 608/768. H2 never hits HBM.
__global__ __launch_bounds__(THREADS, 4) void k_tail(const int* __restrict__ A2,
                                                     const vi4* __restrict__ W2m,
                                                     const int* __restrict__ IDI,
                                                     const float* SC, int* IS,
                                                     const float* __restrict__ wq2,
                                                     const float* __restrict__ b2,
                                                     const float* __restrict__ wqid,
                                                     const float* __restrict__ bidp,
                                                     float* __restrict__ out) {
  __shared__ __align__(16) int lds[4 * 30 * 68];  // 32640B; reused for sums [128][57] f32
  __shared__ int redA[4];
  __shared__ float redF[4];
  __shared__ int sMh2;
  __shared__ float sOutS;
  const int tid = threadIdx.x;
  const int bx = blockIdx.x;
  const int n = bx / 28, rr = bx % 28;
  const int hp = rr >> 1, nh = rr & 1;
  const int ho0 = hp * 2;
  vi4 zero = {0, 0, 0, 0};

  for (int r = 0; r < 4; ++r) {
    int h = ho0 - 1 + r;
    int* dst = lds + r * 30 * 68;
    if (h >= 0 && h < 28) {
      const vi4* src = (const vi4*)(A2 + (n * 28 + h) * 28 * 64);
      for (int i4 = tid; i4 < 448; i4 += THREADS) {
        int col = i4 >> 4, c = (i4 & 15) * 4;
        *(vi4*)(dst + (col + 1) * 68 + c) = src[i4];
      }
      if (tid < 64) dst[tid] = 0;
      else if (tid >= 128 && tid < 192) dst[29 * 68 + (tid - 128)] = 0;
    } else {
      for (int i4 = tid; i4 < 510; i4 += THREADS) ((vi4*)dst)[i4] = zero;
    }
  }
  __syncthreads();

  const int lane = tid & 63, wv = tid >> 6;
  const int mw = wv & 1, nw = wv >> 1;
  const int lm = lane & 15, quad = lane >> 4;
  const int woc0 = lm, woc1 = (16 + lm) > 27 ? 27 : (16 + lm);
  const int choff = quad * 4;
  const int ctbase = nh * 8 + nw * 4;

  vi4 acc[2][4];
  vi4 bA[4], bB[4];
  vi4 a0A, a1A, a0B, a1B;
#pragma unroll
  for (int mt = 0; mt < 2; ++mt)
#pragma unroll
    for (int ct = 0; ct < 4; ++ct) acc[mt][ct] = zero;

  const vi4* wbase = W2m + ctbase * 64 + lane;
#pragma unroll
  for (int ct = 0; ct < 4; ++ct) bA[ct] = wbase[ct * 64];
  {
    const int ro = mw * 30;  // ks=0
    a0A = *(const vi4*)(lds + (ro + woc0) * 68 + choff);
    a1A = *(const vi4*)(lds + (ro + woc1) * 68 + choff);
  }
#pragma unroll 1
  for (int ks = 0; ks < 36; ks += 2) {
    {
      const int ksn = ks + 1;
      const int khn = (ksn >= 12) + (ksn >= 24);
      const int t2 = ksn - khn * 12;
      const int kwn = t2 >> 2, kcn = t2 & 3;
#pragma unroll
      for (int ct = 0; ct < 4; ++ct) bB[ct] = wbase[ksn * 1024 + ct * 64];
      const int ro = (mw + khn) * 30;
      a0B = *(const vi4*)(lds + (ro + woc0 + kwn) * 68 + kcn * 16 + choff);
      a1B = *(const vi4*)(lds + (ro + woc1 + kwn) * 68 + kcn * 16 + choff);
    }
#pragma unroll
    for (int ct = 0; ct < 4; ++ct) {
      acc[0][ct] = MFMA_I8(a0A, bA[ct], acc[0][ct]);
      acc[1][ct] = MFMA_I8(a1A, bA[ct], acc[1][ct]);
    }
    if (ks + 2 < 36) {
      const int ksn = ks + 2;
      const int khn = (ksn >= 12) + (ksn >= 24);
      const int t2 = ksn - khn * 12;
      const int kwn = t2 >> 2, kcn = t2 & 3;
#pragma unroll
      for (int ct = 0; ct < 4; ++ct) bA[ct] = wbase[ksn * 1024 + ct * 64];
      const int ro = (mw + khn) * 30;
      a0A = *(const vi4*)(lds + (ro + woc0 + kwn) * 68 + kcn * 16 + choff);
      a1A = *(const vi4*)(lds + (ro + woc1 + kwn) * 68 + kcn * 16 + choff);
    }
#pragma unroll
    for (int ct = 0; ct < 4; ++ct) {
      acc[0][ct] = MFMA_I8(a0B, bB[ct], acc[0][ct]);
      acc[1][ct] = MFMA_I8(a1B, bB[ct], acc[1][ct]);
    }
  }

  // ---- block max|h2| straight from acc (H2 never stored) ----
  int am = 0;
#pragma unroll
  for (int ct = 0; ct < 4; ++ct)
#pragma unroll
    for (int mt = 0; mt < 2; ++mt)
#pragma unroll
      for (int r = 0; r < 4; ++r) {
        int wo = mt * 16 + quad * 4 + r;
        if (wo < 28) {
          int v = acc[mt][ct][r];
          am = max(am, v < 0 ? -v : v);
        }
      }
#pragma unroll
  for (int k = 32; k >= 1; k >>= 1) am = max(am, __shfl_xor(am, k));
  if (lane == 0) redA[wv] = am;
  __syncthreads();
  if (tid == 0) {
    int a = max(max(redA[0], redA[1]), max(redA[2], redA[3]));
    atomicMax(IS + 6, a);  // device RMW (coherence point)
  }

  // ---- stage this block's IDI half into LDS, transposed [cl][sp] (pad 57) ----
  int* sumsi = lds;
  float* sums = (float*)lds;
  const int ib = ((n * 28 + ho0) * 28) * 256 + nh * 128;
#pragma unroll
  for (int k = 0; k < 28; ++k) {
    int idx = tid + k * 256;            // 0..7167
    int cl = idx & 127, sp = idx >> 7;  // sp = hl*28+wo
    sumsi[cl * 57 + sp] = IDI[ib + sp * 256 + cl];
  }
  __syncthreads();
  if (tid == 0) {
    gbar(IS, 608, bx);  // B: max|h2| global
    sMh2 = __hip_atomic_load(IS + 6, __ATOMIC_RELAXED, __HIP_MEMORY_SCOPE_SYSTEM);
  }
  __syncthreads();
  const SumParams P = make_params2(SC, (const unsigned*)IS, sMh2);

  // ---- RMW owned slots: sum = z + zi; track |sum| ----
  float fm = 0.0f;
#pragma unroll
  for (int ct = 0; ct < 4; ++ct) {
    const int co = (ctbase + ct) * 16 + lm;
    const int cl = co - nh * 128;
    float w2c = wq2[co], b2c = b2[co], wic = wqid[co], bic = bidp[co];
#pragma unroll
    for (int mt = 0; mt < 2; ++mt)
#pragma unroll
      for (int r = 0; r < 4; ++r) {
        int wo = mt * 16 + quad * 4 + r;
        if (wo < 28) {
          int slot = cl * 57 + mw * 28 + wo;
          float sv = sum_val(acc[mt][ct][r], sumsi[slot], P, w2c, b2c, wic, bic);
          sums[slot] = sv;
          fm = fmaxf(fm, fabsf(sv));
        }
      }
  }
#pragma unroll
  for (int k = 32; k >= 1; k >>= 1) fm = fmaxf(fm, __shfl_xor(fm, k));
  if (lane == 0) redF[wv] = fm;
  __syncthreads();
  if (tid == 0) {
    float a = fmaxf(fmaxf(redF[0], redF[1]), fmaxf(redF[2], redF[3]));
    atomicMax(IS + 11, __float_as_int(a));
    gbar(IS, 768, bx);  // B: max|sum| global
    int mb = __hip_atomic_load(IS + 11, __ATOMIC_RELAXED, __HIP_MEMORY_SCOPE_SYSTEM);
    sOutS = fmaxf(__int_as_float(mb) / 127.0f, 1e-8f);
  }
  __syncthreads();
  const float out_s = sOutS;

  // ---- requant + relu, NCHW write ----
  float* ob = out + n * 200704 + (nh * 128) * 784 + ho0 * 28;
#pragma unroll
  for (int k = 0; k < 28; ++k) {
    int idx = tid + k * 256;
    int cl = idx / 56, rem = idx % 56;
    float sv = sums[cl * 57 + rem];
    float q = clamp8f(rintf(sv / out_s));
    ob[cl * 784 + rem] = q > 0.0f ? q * out_s : 0.0f;
  }
  if (bx == 0 && tid == 0) out[6422528] = out_s;
}

extern "C" void kernel_launch(void* const* d_in, const int* in_sizes, int n_in, void* d_out,
                              int out_size, void* d_ws, size_t ws_size, hipStream_t stream) {
  (void)in_sizes; (void)n_in; (void)out_size; (void)ws_size;
  const float* x = (const float*)d_in[0];
  const float* w1 = (const float*)d_in[1];
  const float* w2 = (const float*)d_in[2];
  const float* wid = (const float*)d_in[3];
  const float* bn1g = (const float*)d_in[4];
  const float* bn1b = (const float*)d_in[5];
  const float* bn1m = (const float*)d_in[6];
  const float* bn1v = (const float*)d_in[7];
  const float* bn2g = (const float*)d_in[8];
  const float* bn2b = (const float*)d_in[9];
  const float* bn2m = (const float*)d_in[10];
  const float* bn2v = (const float*)d_in[11];
  const float* idg = (const float*)d_in[12];
  const float* idb = (const float*)d_in[13];
  const float* idm = (const float*)d_in[14];
  const float* idv = (const float*)d_in[15];

  char* ws = (char*)d_ws;
  float* SC = (float*)ws;
  int* IS = (int*)ws;
  unsigned* ISu = (unsigned*)ws;
  // barrier counters occupy IS[128..928); per-channel tables moved past them:
  float* wq1 = (float*)(ws + 4096);
  float* b1 = (float*)(ws + 5120);
  float* wq2 = (float*)(ws + 6144);
  float* b2 = (float*)(ws + 7168);
  float* wqid = (float*)(ws + 8192);
  float* bid = (float*)(ws + 9216);
  char* X8 = ws + 16384;  // NHWC int8; A2 overlays (all X8 reads grid-complete before B1<B3)
  char* A2 = X8;
  char* W1m = X8 + 12845056;
  char* W2m = W1m + 294912;
  char* Widm = W2m + 589824;
  int* IDI = (int*)(Widm + 32768);
  float* out = (float*)d_out;
  int* maxS2 = (int*)d_out;  // extrema scratch in d_out (dead until k_tail's out write)
  int* minS2 = maxS2 + 896 * 256;

  k_pre<<<723, THREADS, 0, stream>>>(IS, bn1g, bn1b, bn1m, bn1v, wq1, b1, bn2g, bn2b, bn2m, bn2v,
                                     wq2, b2, idg, idb, idm, idv, wqid, bid, (const float4*)w1,
                                     (const float4*)w2, (const float4*)wid, (const float4*)x);
  k_quant<<<2016, THREADS, 0, stream>>>(x, (int*)X8, w1, (vi4*)W1m, w2, (vi4*)W2m, wid,
                                        (vi4*)Widm, ISu);
  k_cv1<<<GRID_BLOCKS, THREADS, 0, stream>>>((const int*)X8, (const vi4*)W1m, (const vi4*)Widm,
                                             IDI, (int*)A2, IS, wq1, b1, SC, maxS2, minS2);
  k_tail<<<GRID_BLOCKS, THREADS, 0, stream>>>((const int*)A2, (const vi4*)W2m, (const int*)IDI, SC,
                                              IS, wq2, b2, wqid, bid, out);
}

// Round 12
// 239.238 us; speedup vs baseline: 1.3147x; 1.0443x over previous
//
#include <hip/hip_runtime.h>
#include <limits.h>

#define THREADS 256
#define GRID_BLOCKS 896

typedef int vi4 __attribute__((ext_vector_type(4)));

__device__ __forceinline__ float clamp8f(float q) { return fminf(fmaxf(q, -128.0f), 127.0f); }
__device__ __forceinline__ float sc_from_bits(unsigned b) {
  return fmaxf(__uint_as_float(b) / 127.0f, 1e-8f);
}
__device__ __forceinline__ signed char q8(float v, float s) {
  return (signed char)(int)clamp8f(rintf(v / s));
}

// ===== r12: merge k_cv1 + k_tail into ONE kernel (k_ct). IDI (51.4MB round trip) eliminated:
// block bx's identity acc feeds the residual sum DIRECTLY from registers (identical per-thread
// (lane,wave)->(wo,co,row) mapping in producer and consumer). A2 moves to a fresh region
// (no X8 alias), written agent-scope (proven extrema-scratch pattern), one extra gbar (B4).
// Session ledger: r1 coop-launch not capturable; r2 acquire-poll = L2 maintenance storm;
// r3 fence-free barrier works; r4 cv1-fusion 246.9us BEST (reproduced r11 249.8);
// r5/r7 VGPR-capped fronts spill/starve; r6/r8/r9 deconfound: cv1-r5 rewrite was the +12us.
// Scalar slots: [0] amax_x [1] amax_w1 [2] amax_w2 [3] amax_wid
// [4] maxabs_h1 [5] maxabs_id [6] maxabs_h2 [7] max_y2(rf) [11] amax_sum
// Grid barriers (zeroed by k_pre b==0, IS[128..1088)): bases 128,288,448,608,768,928.
// Per base B: subs B+s*16 (s<8, 112 blocks), root B+128, flag B+144. Max idx 1072 < 1152.
// Channel tables start at IS[1152] (ws+4608). Signed atomicMax; 0xAA poison negative.

__device__ __forceinline__ void gbar(int* IS, int base, int bx) {
  // fence-free barrier (r3-proven): relaxed hierarchical arrive + relaxed system poll.
  // Caller: __syncthreads() before (drains all waves' vmem incl. agent stores) and after.
  asm volatile("s_waitcnt vmcnt(0)" ::: "memory");  // tid0's own RMWs complete before arrive
  int old = __hip_atomic_fetch_add(IS + base + (bx & 7) * 16, 1, __ATOMIC_RELAXED,
                                   __HIP_MEMORY_SCOPE_AGENT);
  if (old == 111) {
    int r = __hip_atomic_fetch_add(IS + base + 128, 1, __ATOMIC_RELAXED, __HIP_MEMORY_SCOPE_AGENT);
    if (r == 7)
      __hip_atomic_fetch_add(IS + base + 144, 1, __ATOMIC_RELAXED, __HIP_MEMORY_SCOPE_AGENT);
  }
  while (__hip_atomic_load(IS + base + 144, __ATOMIC_RELAXED, __HIP_MEMORY_SCOPE_SYSTEM) == 0)
    __builtin_amdgcn_s_sleep(2);
}

__device__ __forceinline__ void amax_body(const float4* __restrict__ p, int n4, int bid,
                                          int nblocks, int* __restrict__ slot) {
  const int tid = threadIdx.x;
  const int stride = nblocks * THREADS;
  float m = 0.0f;
  int i = bid * THREADS + tid;
  for (; i + 3 * stride < n4; i += 4 * stride) {
    float4 v0 = p[i];
    float4 v1 = p[i + stride];
    float4 v2 = p[i + 2 * stride];
    float4 v3 = p[i + 3 * stride];
    float m0 = fmaxf(fmaxf(fabsf(v0.x), fabsf(v0.y)), fmaxf(fabsf(v0.z), fabsf(v0.w)));
    float m1 = fmaxf(fmaxf(fabsf(v1.x), fabsf(v1.y)), fmaxf(fabsf(v1.z), fabsf(v1.w)));
    float m2 = fmaxf(fmaxf(fabsf(v2.x), fabsf(v2.y)), fmaxf(fabsf(v2.z), fabsf(v2.w)));
    float m3 = fmaxf(fmaxf(fabsf(v3.x), fabsf(v3.y)), fmaxf(fabsf(v3.z), fabsf(v3.w)));
    m = fmaxf(m, fmaxf(fmaxf(m0, m1), fmaxf(m2, m3)));
  }
  for (; i < n4; i += stride) {
    float4 v = p[i];
    m = fmaxf(m, fmaxf(fmaxf(fabsf(v.x), fabsf(v.y)), fmaxf(fabsf(v.z), fabsf(v.w))));
  }
#pragma unroll
  for (int k = 32; k >= 1; k >>= 1) m = fmaxf(m, __shfl_xor(m, k));
  __shared__ float wred[4];
  if ((tid & 63) == 0) wred[tid >> 6] = m;
  __syncthreads();
  if (tid == 0) {
    m = fmaxf(fmaxf(wred[0], wred[1]), fmaxf(wred[2], wred[3]));
    atomicMax(slot, __float_as_int(m));
  }
}

// Merged: blocks 0-2 bnfold(bn1,bn2,id); 3..66 w1 amax; 67..194 w2; 195..210 wid; 211..722 x.
// Block 0 also zeroes all grid-barrier counters (IS[128..1088)) for this launch/replay.
__global__ __launch_bounds__(THREADS) void k_pre(
    int* IS, const float* g1, const float* be1, const float* m1, const float* v1, float* wq1,
    float* b1, const float* g2, const float* be2, const float* m2, const float* v2, float* wq2,
    float* b2, const float* gi, const float* bei, const float* mi, const float* vvi, float* wqi,
    float* bi, const float4* w1, const float4* w2, const float4* wid, const float4* x) {
  int b = blockIdx.x;
  int c = threadIdx.x;
  if (b < 3) {
    if (b == 0) {
      IS[128 + c] = 0;
      IS[384 + c] = 0;
      IS[640 + c] = 0;
      if (c < 192) IS[896 + c] = 0;
    }
    const float *gamma, *beta, *mean, *var;
    float *wq, *bb;
    if (b == 0) { gamma = g1; beta = be1; mean = m1; var = v1; wq = wq1; bb = b1; }
    else if (b == 1) { gamma = g2; beta = be2; mean = m2; var = v2; wq = wq2; bb = b2; }
    else { gamma = gi; beta = bei; mean = mi; var = vvi; wq = wqi; bb = bi; }
    __shared__ float red[THREADS];
    float ws = gamma[c] * (1.0f / sqrtf(var[c] + 1e-5f));
    red[c] = fabsf(ws);
    __syncthreads();
    for (int s = THREADS / 2; s > 0; s >>= 1) {
      if (c < s) red[c] = fmaxf(red[c], red[c + s]);
      __syncthreads();
    }
    float sws = fmaxf(red[0] / 127.0f, 1e-8f);
    float q = clamp8f(rintf(ws / sws)) * sws;
    wq[c] = q;
    bb[c] = beta[c] - mean[c] * q;
    return;
  }
  b -= 3;
  if (b < 64) { amax_body(w1, 73728, b, 64, IS + 1); return; }
  b -= 64;
  if (b < 128) { amax_body(w2, 147456, b, 128, IS + 2); return; }
  b -= 128;
  if (b < 16) { amax_body(wid, 8192, b, 16, IS + 3); return; }
  b -= 16;
  amax_body(x, 3211264, b, 512, IS + 0);
}

// Merged quantize: blocks [0,1792) qx; [1792,1864) qw1; [1864,2008) qw2; [2008,2016) qwid.
__global__ __launch_bounds__(THREADS) void k_quant(const float* __restrict__ x,
                                                   int* __restrict__ X8,
                                                   const float* __restrict__ w1f,
                                                   vi4* __restrict__ W1m,
                                                   const float* __restrict__ w2f,
                                                   vi4* __restrict__ W2m,
                                                   const float* __restrict__ widf,
                                                   vi4* __restrict__ Widm,
                                                   const unsigned* __restrict__ ISu) {
  __shared__ signed char tile[56 * 132];
  int b = blockIdx.x;
  int t = threadIdx.x;
  if (b < 1792) {
    float s = sc_from_bits(ISu[0]);
    int h = b % 56, n = b / 56;
    const float* xp = x + ((n * 128) * 56 + h) * 56;
#pragma unroll
    for (int k = 0; k < 28; ++k) {
      int i = t + k * 256;  // < 7168
      int w = i % 56, c = i / 56;
      tile[w * 132 + c] = q8(xp[c * 3136 + w], s);
    }
    __syncthreads();
    int* op = X8 + (n * 56 + h) * 56 * 32;
#pragma unroll
    for (int k = 0; k < 7; ++k) {
      int i = t + k * 256;  // < 1792
      int w = i >> 5, c4 = (i & 31) * 4;
      const signed char* tp = tile + w * 132 + c4;
      op[i] = (int)(unsigned char)tp[0] | ((int)(unsigned char)tp[1] << 8) |
              ((int)(unsigned char)tp[2] << 16) | ((int)(unsigned char)tp[3] << 24);
    }
    return;
  }
  if (b < 1864) {
    int tt = (b - 1792) * THREADS + t;  // < 18432
    float s = sc_from_bits(ISu[1]);
    int lane = tt & 63;
    int cotile = (tt >> 6) & 15;
    int ks = tt >> 10;  // 0..17
    int tap = ks >> 1, kc = ks & 1;
    int kh = tap / 3, kw = tap % 3;
    int co = cotile * 16 + (lane & 15);
    int ci0 = kc * 64 + (lane >> 4) * 16;
    const float* src = w1f + (co * 128 + ci0) * 9 + kh * 3 + kw;
    int r[4];
#pragma unroll
    for (int q = 0; q < 4; ++q) {
      unsigned b0 = (unsigned char)q8(src[(q * 4 + 0) * 9], s);
      unsigned b1 = (unsigned char)q8(src[(q * 4 + 1) * 9], s);
      unsigned b2 = (unsigned char)q8(src[(q * 4 + 2) * 9], s);
      unsigned b3 = (unsigned char)q8(src[(q * 4 + 3) * 9], s);
      r[q] = (int)(b0 | (b1 << 8) | (b2 << 16) | (b3 << 24));
    }
    vi4 v = {r[0], r[1], r[2], r[3]};
    W1m[tt] = v;
    return;
  }
  if (b < 2008) {
    int tt = (b - 1864) * THREADS + t;  // < 36864
    float s = sc_from_bits(ISu[2]);
    int lane = tt & 63;
    int cotile = (tt >> 6) & 15;
    int ks = tt >> 10;  // 0..35
    int tap = ks >> 2, kc = ks & 3;
    int kh = tap / 3, kw = tap % 3;
    int co = cotile * 16 + (lane & 15);
    int ci0 = kc * 64 + (lane >> 4) * 16;
    const float* src = w2f + (co * 256 + ci0) * 9 + kh * 3 + kw;
    int r[4];
#pragma unroll
    for (int q = 0; q < 4; ++q) {
      unsigned b0 = (unsigned char)q8(src[(q * 4 + 0) * 9], s);
      unsigned b1 = (unsigned char)q8(src[(q * 4 + 1) * 9], s);
      unsigned b2 = (unsigned char)q8(src[(q * 4 + 2) * 9], s);
      unsigned b3 = (unsigned char)q8(src[(q * 4 + 3) * 9], s);
      r[q] = (int)(b0 | (b1 << 8) | (b2 << 16) | (b3 << 24));
    }
    vi4 v = {r[0], r[1], r[2], r[3]};
    W2m[tt] = v;
    return;
  }
  {
    int tt = (b - 2008) * THREADS + t;  // < 2048
    float s = sc_from_bits(ISu[3]);
    int lane = tt & 63;
    int cotile = (tt >> 6) & 15;
    int ks = tt >> 10;  // 0..1
    int co = cotile * 16 + (lane & 15);
    int ci0 = ks * 64 + (lane >> 4) * 16;
    const float* src = widf + co * 128 + ci0;
    int r[4];
#pragma unroll
    for (int q = 0; q < 4; ++q) {
      unsigned b0 = (unsigned char)q8(src[q * 4 + 0], s);
      unsigned b1 = (unsigned char)q8(src[q * 4 + 1], s);
      unsigned b2 = (unsigned char)q8(src[q * 4 + 2], s);
      unsigned b3 = (unsigned char)q8(src[q * 4 + 3], s);
      r[q] = (int)(b0 | (b1 << 8) | (b2 << 16) | (b3 << 24));
    }
    vi4 v = {r[0], r[1], r[2], r[3]};
    Widm[tt] = v;
  }
}

#define MFMA_I8(a, b, c) __builtin_amdgcn_mfma_i32_16x16x64_i8(a, b, c, 0, 0, 0)

// quant(h1) -> bn1 -> relu -> quant (scalar form, used in qh1 phase)
__device__ __forceinline__ signed char qact(int v, float sxw, float s_h1, float s_y2, float wq,
                                            float bb) {
  float hf = (float)v * sxw;
  float q = clamp8f(rintf(hf / s_h1));
  float hv = q * s_h1;
  float y = fmaxf(hv * wq + bb, 0.0f);
  float a = fminf(fmaxf(rintf(y / s_y2), -128.0f), 127.0f);
  return (signed char)(int)a;
}

__device__ __forceinline__ float sc_slot(const int* IS, int slot) {
  unsigned u = (unsigned)__hip_atomic_load((int*)(IS + slot), __ATOMIC_RELAXED,
                                           __HIP_MEMORY_SCOPE_AGENT);
  return fmaxf(__uint_as_float(u) / 127.0f, 1e-8f);
}

// ---- residual sum math ----
struct SumParams {
  float sxw2, s_h2, sxwid, s_idq;
};
__device__ __forceinline__ float sum_val(int v2, int vi, const SumParams& P, float wq2c, float b2c,
                                         float wqidc, float bidc) {
  float q2 = clamp8f(rintf((float)v2 * P.sxw2 / P.s_h2));
  float z = (q2 * P.s_h2) * wq2c + b2c;
  float qi = clamp8f(rintf((float)vi * P.sxwid / P.s_idq));
  float zi = (qi * P.s_idq) * wqidc + bidc;
  return z + zi;
}

// Fused conv1+conv2 stage: conv1 3x3 s2 p1 + identity 1x1 s2 (acc kept in REGISTERS through
// the whole kernel) + grid scale derivation + qh1 -> A2 (agent stores, fresh region) + conv2
// 3x3 s1 p1 + residual (identity from registers!) + requant + NCHW out. SIX fence-free
// barriers (128,288,448,608,768,928). H1, H2, IDI never touch HBM.
// (256,4): LDS 37.1KB -> 1024 slots >= 896 co-resident by construction.
__global__ __launch_bounds__(THREADS, 4) void k_ct(
    const int* X8, const vi4* __restrict__ W1m, const vi4* __restrict__ Widm,
    const vi4* __restrict__ W2m, int* A2p, int* IS, const float* __restrict__ wq1,
    const float* __restrict__ b1, const float* __restrict__ wq2, const float* __restrict__ b2,
    const float* __restrict__ wqid, const float* __restrict__ bidp, float* __restrict__ out,
    int* maxS2, int* minS2) {
  __shared__ __align__(16) int lds[9280];  // stage1 5*58*32 | park h1 [56][130]+reduce |
                                           // stage2 4*30*68 | sums [128][57] f32
  __shared__ int redA[4], redH[4];
  __shared__ int sVmax, sVmin;
  __shared__ float redF[4];
  __shared__ float sSxw, sSh1, sSy2, sSxwid, sSidq, sSxw2;
  __shared__ int sMh2;
  __shared__ float sOutS;
  const int tid = threadIdx.x;
  const int bx = blockIdx.x;
  const int n = bx / 28, rr = bx % 28;
  const int hp = rr >> 1, nh = rr & 1;
  const int ho0 = hp * 2;
  vi4 zero = {0, 0, 0, 0};

  // ---- stage1: 5 input rows, swizzled stride-32 ----
  for (int r = 0; r < 5; ++r) {
    int h = 2 * ho0 - 1 + r;
    int* dst = lds + r * 58 * 32;
    if (h >= 0 && h < 56) {
      const vi4* src = (const vi4*)(X8 + (n * 56 + h) * 56 * 32);
      for (int i4 = tid; i4 < 448; i4 += THREADS) {
        int col = i4 >> 3, e0 = (i4 & 7) * 4;
        int cell = r * 58 + col + 1;
        *(vi4*)(lds + cell * 32 + (e0 ^ ((cell & 7) << 2))) = src[i4];
      }
      if (tid < 32) dst[tid] = 0;
      else if (tid >= 128 && tid < 160) dst[57 * 32 + (tid - 128)] = 0;
    } else {
      for (int i4 = tid; i4 < 464; i4 += THREADS) ((vi4*)dst)[i4] = zero;
    }
  }
  __syncthreads();

  const int lane = tid & 63, wv = tid >> 6;
  const int mw = wv & 1, nw = wv >> 1;
  const int lm = lane & 15, quad = lane >> 4;
  const int woc0 = lm, woc1 = (16 + lm) > 27 ? 27 : (16 + lm);
  const int choff = quad * 4;
  const int ctbase = nh * 8 + nw * 4;

#define LDA(row, colp, sub)                                                              \
  (*(const vi4*)(lds + ((row) * 58 + (colp)) * 32 +                                      \
                 ((sub) ^ ((((row) * 58 + (colp)) & 7) << 2))))

  vi4 acc[2][4];
  vi4 accI[2][4];  // identity branch accumulator — LIVES IN REGISTERS until residual phase
  vi4 bA[4], bB[4];
  vi4 a0A, a1A, a0B, a1B;

  // ---- identity branch (2 K-steps) -> accI ----
#pragma unroll
  for (int mt = 0; mt < 2; ++mt)
#pragma unroll
    for (int ct = 0; ct < 4; ++ct) accI[mt][ct] = zero;
  const vi4* wibase = Widm + ctbase * 64 + lane;
  {
    const int row = 2 * mw + 1;
#pragma unroll
    for (int kc = 0; kc < 2; ++kc) {
      vi4 a0 = LDA(row, 2 * woc0 + 1, kc * 16 + choff);
      vi4 a1 = LDA(row, 2 * woc1 + 1, kc * 16 + choff);
#pragma unroll
      for (int ct = 0; ct < 4; ++ct) {
        vi4 b = wibase[kc * 1024 + ct * 64];
        accI[0][ct] = MFMA_I8(a0, b, accI[0][ct]);
        accI[1][ct] = MFMA_I8(a1, b, accI[1][ct]);
      }
    }
  }
  int am = 0;
#pragma unroll
  for (int ct = 0; ct < 4; ++ct)
#pragma unroll
    for (int mt = 0; mt < 2; ++mt)
#pragma unroll
      for (int r = 0; r < 4; ++r) {
        int wo = mt * 16 + quad * 4 + r;
        if (wo < 28) {
          int v = accI[mt][ct][r];
          am = max(am, v < 0 ? -v : v);
        }
      }
#pragma unroll
  for (int k = 32; k >= 1; k >>= 1) am = max(am, __shfl_xor(am, k));
  if (lane == 0) redA[wv] = am;

  // ---- main 3x3 conv1, 18 K-steps, ping-pong -> acc ----
#pragma unroll
  for (int mt = 0; mt < 2; ++mt)
#pragma unroll
    for (int ct = 0; ct < 4; ++ct) acc[mt][ct] = zero;
  const vi4* wbase = W1m + ctbase * 64 + lane;
#pragma unroll
  for (int ct = 0; ct < 4; ++ct) bA[ct] = wbase[ct * 64];
  {
    a0A = LDA(2 * mw, 2 * woc0, choff);
    a1A = LDA(2 * mw, 2 * woc1, choff);
  }
#pragma unroll 1
  for (int ks = 0; ks < 18; ks += 2) {
    {
      const int ksn = ks + 1;
      const int khn = (ksn >= 6) + (ksn >= 12);
      const int t2 = ksn - khn * 6;
      const int kwn = t2 >> 1, kcn = t2 & 1;
#pragma unroll
      for (int ct = 0; ct < 4; ++ct) bB[ct] = wbase[ksn * 1024 + ct * 64];
      const int row = 2 * mw + khn;
      a0B = LDA(row, 2 * woc0 + kwn, kcn * 16 + choff);
      a1B = LDA(row, 2 * woc1 + kwn, kcn * 16 + choff);
    }
#pragma unroll
    for (int ct = 0; ct < 4; ++ct) {
      acc[0][ct] = MFMA_I8(a0A, bA[ct], acc[0][ct]);
      acc[1][ct] = MFMA_I8(a1A, bA[ct], acc[1][ct]);
    }
    if (ks + 2 < 18) {
      const int ksn = ks + 2;
      const int khn = (ksn >= 6) + (ksn >= 12);
      const int t2 = ksn - khn * 6;
      const int kwn = t2 >> 1, kcn = t2 & 1;
#pragma unroll
      for (int ct = 0; ct < 4; ++ct) bA[ct] = wbase[ksn * 1024 + ct * 64];
      const int row = 2 * mw + khn;
      a0A = LDA(row, 2 * woc0 + kwn, kcn * 16 + choff);
      a1A = LDA(row, 2 * woc1 + kwn, kcn * 16 + choff);
    }
#pragma unroll
    for (int ct = 0; ct < 4; ++ct) {
      acc[0][ct] = MFMA_I8(a0B, bB[ct], acc[0][ct]);
      acc[1][ct] = MFMA_I8(a1B, bB[ct], acc[1][ct]);
    }
  }
#undef LDA

  // ---- per-channel extrema -> d_out scratch via AGENT stores (cross-XCD visible) ----
#pragma unroll
  for (int ct = 0; ct < 4; ++ct) {
    int vmax = INT_MIN, vmin = INT_MAX;
#pragma unroll
    for (int mt = 0; mt < 2; ++mt)
#pragma unroll
      for (int r = 0; r < 4; ++r) {
        int wo = mt * 16 + quad * 4 + r;
        if (wo < 28) {
          int v = acc[mt][ct][r];
          vmax = max(vmax, v);
          vmin = min(vmin, v);
        }
      }
    vmax = max(vmax, __shfl_xor(vmax, 16));
    vmax = max(vmax, __shfl_xor(vmax, 32));
    vmin = min(vmin, __shfl_xor(vmin, 16));
    vmin = min(vmin, __shfl_xor(vmin, 32));
    if (lane < 16) {
      int cl = (nw * 4 + ct) * 16 + lane;
      __hip_atomic_store(maxS2 + bx * 256 + mw * 128 + cl, vmax, __ATOMIC_RELAXED,
                         __HIP_MEMORY_SCOPE_AGENT);
      __hip_atomic_store(minS2 + bx * 256 + mw * 128 + cl, vmin, __ATOMIC_RELAXED,
                         __HIP_MEMORY_SCOPE_AGENT);
    }
  }

  __syncthreads();  // stage1 reads done; redA ready; all waves' stores drained
  if (tid == 0) {
    int a = max(max(redA[0], redA[1]), max(redA[2], redA[3]));
    atomicMax(IS + 5, a);  // id amax (device RMW)
  }
  // ---- park h1 into LDS [sp=mw*28+wo][130] (stage1 dead) ----
#pragma unroll
  for (int ct = 0; ct < 4; ++ct) {
    const int cl = (nw * 4 + ct) * 16 + lm;
#pragma unroll
    for (int mt = 0; mt < 2; ++mt)
#pragma unroll
      for (int r = 0; r < 4; ++r) {
        int wo = mt * 16 + quad * 4 + r;
        if (wo < 28) lds[(mw * 28 + wo) * 130 + cl] = acc[mt][ct][r];
      }
  }
  __syncthreads();
  if (tid == 0) gbar(IS, 128, bx);  // B1: extrema + IS[5] global
  __syncthreads();

  // ---- rs1a: 256 blocks reduce per-channel extrema ----
  if (bx < 256) {
    const int c = bx, nhc = c >> 7, cl = c & 127;
    int vmax = INT_MIN, vmin = INT_MAX;
    for (int j = tid; j < 896; j += THREADS) {
      int bxx = nhc + ((j >> 1) << 1);
      int mwj = j & 1;
      int a = __hip_atomic_load(maxS2 + bxx * 256 + mwj * 128 + cl, __ATOMIC_RELAXED,
                                __HIP_MEMORY_SCOPE_AGENT);
      int i_ = __hip_atomic_load(minS2 + bxx * 256 + mwj * 128 + cl, __ATOMIC_RELAXED,
                                 __HIP_MEMORY_SCOPE_AGENT);
      vmax = max(vmax, a);
      vmin = min(vmin, i_);
    }
    int* rMax = lds + 7280;
    int* rMin = lds + 7536;
    rMax[tid] = vmax;
    rMin[tid] = vmin;
    __syncthreads();
    for (int s = 128; s > 0; s >>= 1) {
      if (tid < s) {
        rMax[tid] = max(rMax[tid], rMax[tid + s]);
        rMin[tid] = min(rMin[tid], rMin[tid + s]);
      }
      __syncthreads();
    }
    if (tid == 0) {
      sVmax = rMax[0];
      sVmin = rMin[0];
      int a1 = sVmax < 0 ? -sVmax : sVmax;
      int a0 = sVmin < 0 ? -sVmin : sVmin;
      atomicMax(IS + 4, max(a1, a0));  // mh1
    }
  }
  __syncthreads();
  if (tid == 0) gbar(IS, 288, bx);  // B2: mh1 global
  __syncthreads();

  // ---- rs1b: per-channel rf -> IS[7] ----
  if (bx < 256 && tid == 0) {
    float sx = sc_slot(IS, 0);
    float sw1 = sc_slot(IS, 1);
    int mh1 = __hip_atomic_load(IS + 4, __ATOMIC_RELAXED, __HIP_MEMORY_SCOPE_AGENT);
    float sxw = sx * sw1;
    float s_h1 = fmaxf(sxw * (float)mh1 / 127.0f, 1e-8f);
    float wq = wq1[bx], bbc = b1[bx];
    float q1 = clamp8f(rintf((float)sVmax * sxw / s_h1));
    float q0 = clamp8f(rintf((float)sVmin * sxw / s_h1));
    float y1 = fmaxf(q1 * s_h1 * wq + bbc, 0.0f);
    float y0 = fmaxf(q0 * s_h1 * wq + bbc, 0.0f);
    atomicMax(IS + 7, __float_as_int(fmaxf(y1, y0)));  // rf >= 0
  }
  __syncthreads();
  if (tid == 0) gbar(IS, 448, bx);  // B3: rf global
  __syncthreads();

  // ---- scales, all local (no SC persistence needed) ----
  if (tid == 0) {
    float sx = sc_slot(IS, 0);
    float sw1 = sc_slot(IS, 1);
    int mh1 = __hip_atomic_load(IS + 4, __ATOMIC_RELAXED, __HIP_MEMORY_SCOPE_AGENT);
    int mrf = __hip_atomic_load(IS + 7, __ATOMIC_RELAXED, __HIP_MEMORY_SCOPE_AGENT);
    float sxw = sx * sw1;
    sSxw = sxw;
    sSh1 = fmaxf(sxw * (float)mh1 / 127.0f, 1e-8f);
    float s_y2 = fmaxf(__int_as_float(mrf) / 127.0f, 1e-8f);
    sSy2 = s_y2;
    int mid = __hip_atomic_load(IS + 5, __ATOMIC_RELAXED, __HIP_MEMORY_SCOPE_AGENT);
    float swid = sc_slot(IS, 3);
    sSxwid = sx * swid;
    sSidq = fmaxf(sx * swid * (float)mid / 127.0f, 1e-8f);
    sSxw2 = s_y2 * sc_slot(IS, 2);
  }
  __syncthreads();

  // ---- qh1 from parked LDS -> A2 via AGENT stores (fresh region, no X8 alias) ----
  {
    const float sxw = sSxw, s_h1 = sSh1, s_y2 = sSy2;
#pragma unroll
    for (int k = 0; k < 7; ++k) {
      int i = tid + k * 256;  // < 1792
      int sp = i >> 5, c4i = i & 31;
      int mwp = sp >= 28 ? 1 : 0;
      int wo = sp - mwp * 28;
      int c0 = nh * 128 + c4i * 4;
      const int* pk = lds + sp * 130 + c4i * 4;
      unsigned r0 = (unsigned char)qact(pk[0], sxw, s_h1, s_y2, wq1[c0], b1[c0]);
      unsigned r1 = (unsigned char)qact(pk[1], sxw, s_h1, s_y2, wq1[c0 + 1], b1[c0 + 1]);
      unsigned r2 = (unsigned char)qact(pk[2], sxw, s_h1, s_y2, wq1[c0 + 2], b1[c0 + 2]);
      unsigned r3 = (unsigned char)qact(pk[3], sxw, s_h1, s_y2, wq1[c0 + 3], b1[c0 + 3]);
      __hip_atomic_store(A2p + ((n * 28 + ho0 + mwp) * 28 + wo) * 64 + nh * 32 + c4i,
                         (int)(r0 | (r1 << 8) | (r2 << 16) | (r3 << 24)), __ATOMIC_RELAXED,
                         __HIP_MEMORY_SCOPE_AGENT);
    }
  }
  __syncthreads();
  if (tid == 0) gbar(IS, 608, bx);  // B4: A2 global (halo rows from neighbor blocks)
  __syncthreads();

  // ---- stage2: A2 rows ho0-1..ho0+2 -> lds conv2 layout (plain vi4 loads; region was
  //      never read pre-B4 -> no stale L2 lines; agent stores landed at coherence point) ----
  for (int r = 0; r < 4; ++r) {
    int h = ho0 - 1 + r;
    int* dst = lds + r * 30 * 68;
    if (h >= 0 && h < 28) {
      const vi4* src = (const vi4*)(A2p + (n * 28 + h) * 28 * 64);
      for (int i4 = tid; i4 < 448; i4 += THREADS) {
        int col = i4 >> 4, c = (i4 & 15) * 4;
        *(vi4*)(dst + (col + 1) * 68 + c) = src[i4];
      }
      if (tid < 64) dst[tid] = 0;
      else if (tid >= 128 && tid < 192) dst[29 * 68 + (tid - 128)] = 0;
    } else {
      for (int i4 = tid; i4 < 510; i4 += THREADS) ((vi4*)dst)[i4] = zero;
    }
  }
  __syncthreads();

  // ---- conv2 3x3 s1 p1, 36 K-steps, ping-pong -> acc (conv1 acc dead after park) ----
#pragma unroll
  for (int mt = 0; mt < 2; ++mt)
#pragma unroll
    for (int ct = 0; ct < 4; ++ct) acc[mt][ct] = zero;
  const vi4* wbase2 = W2m + ctbase * 64 + lane;
#pragma unroll
  for (int ct = 0; ct < 4; ++ct) bA[ct] = wbase2[ct * 64];
  {
    const int ro = mw * 30;  // ks=0
    a0A = *(const vi4*)(lds + (ro + woc0) * 68 + choff);
    a1A = *(const vi4*)(lds + (ro + woc1) * 68 + choff);
  }
#pragma unroll 1
  for (int ks = 0; ks < 36; ks += 2) {
    {
      const int ksn = ks + 1;
      const int khn = (ksn >= 12) + (ksn >= 24);
      const int t2 = ksn - khn * 12;
      const int kwn = t2 >> 2, kcn = t2 & 3;
#pragma unroll
      for (int ct = 0; ct < 4; ++ct) bB[ct] = wbase2[ksn * 1024 + ct * 64];
      const int ro = (mw + khn) * 30;
      a0B = *(const vi4*)(lds + (ro + woc0 + kwn) * 68 + kcn * 16 + choff);
      a1B = *(const vi4*)(lds + (ro + woc1 + kwn) * 68 + kcn * 16 + choff);
    }
#pragma unroll
    for (int ct = 0; ct < 4; ++ct) {
      acc[0][ct] = MFMA_I8(a0A, bA[ct], acc[0][ct]);
      acc[1][ct] = MFMA_I8(a1A, bA[ct], acc[1][ct]);
    }
    if (ks + 2 < 36) {
      const int ksn = ks + 2;
      const int khn = (ksn >= 12) + (ksn >= 24);
      const int t2 = ksn - khn * 12;
      const int kwn = t2 >> 2, kcn = t2 & 3;
#pragma unroll
      for (int ct = 0; ct < 4; ++ct) bA[ct] = wbase2[ksn * 1024 + ct * 64];
      const int ro = (mw + khn) * 30;
      a0A = *(const vi4*)(lds + (ro + woc0 + kwn) * 68 + kcn * 16 + choff);
      a1A = *(const vi4*)(lds + (ro + woc1 + kwn) * 68 + kcn * 16 + choff);
    }
#pragma unroll
    for (int ct = 0; ct < 4; ++ct) {
      acc[0][ct] = MFMA_I8(a0B, bB[ct], acc[0][ct]);
      acc[1][ct] = MFMA_I8(a1B, bB[ct], acc[1][ct]);
    }
  }

  // ---- block max|h2| straight from acc (H2 never stored) ----
  int am2 = 0;
#pragma unroll
  for (int ct = 0; ct < 4; ++ct)
#pragma unroll
    for (int mt = 0; mt < 2; ++mt)
#pragma unroll
      for (int r = 0; r < 4; ++r) {
        int wo = mt * 16 + quad * 4 + r;
        if (wo < 28) {
          int v = acc[mt][ct][r];
          am2 = max(am2, v < 0 ? -v : v);
        }
      }
#pragma unroll
  for (int k = 32; k >= 1; k >>= 1) am2 = max(am2, __shfl_xor(am2, k));
  if (lane == 0) redH[wv] = am2;
  __syncthreads();  // conv2 LDS reads done; redH visible
  if (tid == 0) {
    atomicMax(IS + 6, max(max(redH[0], redH[1]), max(redH[2], redH[3])));
    gbar(IS, 768, bx);  // B5: max|h2| global
    sMh2 = __hip_atomic_load(IS + 6, __ATOMIC_RELAXED, __HIP_MEMORY_SCOPE_SYSTEM);
  }
  __syncthreads();

  SumParams P;
  P.sxw2 = sSxw2;
  P.s_h2 = fmaxf(sSxw2 * (float)sMh2 / 127.0f, 1e-8f);
  P.sxwid = sSxwid;
  P.s_idq = sSidq;

  // ---- residual: identity comes STRAIGHT FROM accI registers (same (wo,co,row) mapping) ----
  float* sums = (float*)lds;  // [128][57], overwrites conv2 staging (dead)
  float fm = 0.0f;
#pragma unroll
  for (int ct = 0; ct < 4; ++ct) {
    const int co = (ctbase + ct) * 16 + lm;
    const int cl = co - nh * 128;
    float w2c = wq2[co], b2c = b2[co], wic = wqid[co], bic = bidp[co];
#pragma unroll
    for (int mt = 0; mt < 2; ++mt)
#pragma unroll
      for (int r = 0; r < 4; ++r) {
        int wo = mt * 16 + quad * 4 + r;
        if (wo < 28) {
          int slot = cl * 57 + mw * 28 + wo;
          float sv = sum_val(acc[mt][ct][r], accI[mt][ct][r], P, w2c, b2c, wic, bic);
          sums[slot] = sv;
          fm = fmaxf(fm, fabsf(sv));
        }
      }
  }
#pragma unroll
  for (int k = 32; k >= 1; k >>= 1) fm = fmaxf(fm, __shfl_xor(fm, k));
  if (lane == 0) redF[wv] = fm;
  __syncthreads();
  if (tid == 0) {
    float a = fmaxf(fmaxf(redF[0], redF[1]), fmaxf(redF[2], redF[3]));
    atomicMax(IS + 11, __float_as_int(a));
    gbar(IS, 928, bx);  // B6: max|sum| global
    int mb = __hip_atomic_load(IS + 11, __ATOMIC_RELAXED, __HIP_MEMORY_SCOPE_SYSTEM);
    sOutS = fmaxf(__int_as_float(mb) / 127.0f, 1e-8f);
  }
  __syncthreads();
  const float out_s = sOutS;

  // ---- requant + relu, NCHW write ----
  float* ob = out + n * 200704 + (nh * 128) * 784 + ho0 * 28;
#pragma unroll
  for (int k = 0; k < 28; ++k) {
    int idx = tid + k * 256;
    int cl = idx / 56, rem = idx % 56;
    float sv = sums[cl * 57 + rem];
    float q = clamp8f(rintf(sv / out_s));
    ob[cl * 784 + rem] = q > 0.0f ? q * out_s : 0.0f;
  }
  if (bx == 0 && tid == 0) out[6422528] = out_s;
}

extern "C" void kernel_launch(void* const* d_in, const int* in_sizes, int n_in, void* d_out,
                              int out_size, void* d_ws, size_t ws_size, hipStream_t stream) {
  (void)in_sizes; (void)n_in; (void)out_size; (void)ws_size;
  const float* x = (const float*)d_in[0];
  const float* w1 = (const float*)d_in[1];
  const float* w2 = (const float*)d_in[2];
  const float* wid = (const float*)d_in[3];
  const float* bn1g = (const float*)d_in[4];
  const float* bn1b = (const float*)d_in[5];
  const float* bn1m = (const float*)d_in[6];
  const float* bn1v = (const float*)d_in[7];
  const float* bn2g = (const float*)d_in[8];
  const float* bn2b = (const float*)d_in[9];
  const float* bn2m = (const float*)d_in[10];
  const float* bn2v = (const float*)d_in[11];
  const float* idg = (const float*)d_in[12];
  const float* idb = (const float*)d_in[13];
  const float* idm = (const float*)d_in[14];
  const float* idv = (const float*)d_in[15];

  char* ws = (char*)d_ws;
  int* IS = (int*)ws;
  unsigned* ISu = (unsigned*)ws;
  // barrier counters occupy IS[128..1088); per-channel tables after IS[1152]:
  float* wq1 = (float*)(ws + 4608);
  float* b1 = (float*)(ws + 5632);
  float* wq2 = (float*)(ws + 6656);
  float* b2 = (float*)(ws + 7680);
  float* wqid = (float*)(ws + 8704);
  float* bid = (float*)(ws + 9728);
  char* X8 = ws + 16384;  // NHWC int8 (read-only after k_quant; no A2 alias anymore)
  char* W1m = X8 + 12845056;
  char* W2m = W1m + 294912;
  char* Widm = W2m + 589824;
  int* A2p = (int*)(Widm + 32768);  // A2 int8 as ints, fresh region (old IDI space)
  float* out = (float*)d_out;
  int* maxS2 = (int*)d_out;  // extrema scratch in d_out (dead until k_ct's final out write)
  int* minS2 = maxS2 + 896 * 256;

  k_pre<<<723, THREADS, 0, stream>>>(IS, bn1g, bn1b, bn1m, bn1v, wq1, b1, bn2g, bn2b, bn2m, bn2v,
                                     wq2, b2, idg, idb, idm, idv, wqid, bid, (const float4*)w1,
                                     (const float4*)w2, (const float4*)wid, (const float4*)x);
  k_quant<<<2016, THREADS, 0, stream>>>(x, (int*)X8, w1, (vi4*)W1m, w2, (vi4*)W2m, wid,
                                        (vi4*)Widm, ISu);
  k_ct<<<GRID_BLOCKS, THREADS, 0, stream>>>((const int*)X8, (const vi4*)W1m, (const vi4*)Widm,
                                            (const vi4*)W2m, A2p, IS, wq1, b1, wq2, b2, wqid, bid,
                                            out, maxS2, minS2);
}